// Round 4
// baseline (1019.213 us; speedup 1.0000x reference)
//
#include <hip/hip_runtime.h>
#include <math.h>

// Problem constants (B=2, S=4096, D=512, MAXC=32, BIAS_LEN=128, TEMP=1)
#define BB   2
#define SS   4096
#define DD   512
#define DH   256      // D/2
#define KTOP 32
#define KSEL 64       // approx-filter width (one candidate per lane)
#define HALF 2048     // j processed in two halves to bound workspace
#define SCALE 0.044194173824159216f   // 1/sqrt(512)

typedef __bf16 bf16_t;
typedef bf16_t bf16x8 __attribute__((ext_vector_type(8)));
typedef float  f32x4  __attribute__((ext_vector_type(4)));

// decode row of triangular tile list: q in [0, r_max*(r_max+1)/2)
__device__ __forceinline__ int tri_row(int q) {
    int r = (int)((sqrtf(8.0f * q + 1.0f) - 1.0f) * 0.5f);
    while ((r + 1) * (r + 2) / 2 <= q) ++r;
    while (r * (r + 1) / 2 > q) --r;
    return r;
}

// ---------------------------------------------------------------------------
// MLP GEMM v8 (unchanged, verified): 128x128 tile, 8x8 micro, FP32 VALU.
// ---------------------------------------------------------------------------
template<bool GELU>
__global__ __launch_bounds__(256)
void gemm128(const float* __restrict__ A0, const float* __restrict__ A1,
             const float* __restrict__ W0, const float* __restrict__ W1,
             const float* __restrict__ b0, const float* __restrict__ b1,
             float* __restrict__ C0, float* __restrict__ C1,
             int N, int K)
{
    __shared__ float As[32][132];   // [k][m]
    __shared__ float Ws[32][132];   // [k][n]
    const int t = threadIdx.x;
    const int z = blockIdx.z;
    const float* A    = z ? A1 : A0;
    const float* W    = z ? W1 : W0;
    const float* bias = z ? b1 : b0;
    float*       C    = z ? C1 : C0;
    const int n0 = blockIdx.x * 128;
    const int m0 = blockIdx.y * 128;

    const int kq = t & 7;          // A stager: k-quad within chunk
    const int rr = t >> 3;         // A stager: row 0..31 (+u*32)
    const int wkr = t >> 3;        // W stager: k-row 0..31
    const int wnc = (t & 7) * 16;  // W stager: col group (16 cols = 4 float4)
    const float* Ab = A + (size_t)m0 * K;
    const float* Wb = W + (size_t)0 * N + n0;

    const int lane = t & 63, wav = t >> 6;
    const int wr = wav >> 1, wc = wav & 1;     // wave 2x2 over 64x64 regions
    const int li = lane >> 3, lj = lane & 7;   // 8x8 lane grid

    float acc[8][8] = {};
    float4 aR[4], wR[4];
    #pragma unroll
    for (int u = 0; u < 4; ++u) {              // prologue: chunk 0 -> regs
        int r = u * 32 + rr;
        aR[u] = *(const float4*)&Ab[(size_t)r * K + 4 * kq];
        wR[u] = *(const float4*)&Wb[(size_t)wkr * N + wnc + 4 * u];
    }
    const int nch = K >> 5;
    for (int c = 0; c < nch; ++c) {
        __syncthreads();
        #pragma unroll
        for (int u = 0; u < 4; ++u) {          // regs -> LDS
            int r = u * 32 + rr;
            As[4*kq+0][r] = aR[u].x; As[4*kq+1][r] = aR[u].y;
            As[4*kq+2][r] = aR[u].z; As[4*kq+3][r] = aR[u].w;
            *(float4*)&Ws[wkr][wnc + 4 * u] = wR[u];
        }
        __syncthreads();
        if (c + 1 < nch) {                     // prefetch next chunk
            int k0 = (c + 1) * 32;
            #pragma unroll
            for (int u = 0; u < 4; ++u) {
                int r = u * 32 + rr;
                aR[u] = *(const float4*)&Ab[(size_t)r * K + k0 + 4 * kq];
                wR[u] = *(const float4*)&Wb[(size_t)(k0 + wkr) * N + wnc + 4 * u];
            }
        }
        #pragma unroll
        for (int kk = 0; kk < 32; ++kk) {      // conflict-free: 8 addrs x 8-bcast
            float4 a0 = *(const float4*)&As[kk][wr * 64 + li * 8];
            float4 a1 = *(const float4*)&As[kk][wr * 64 + li * 8 + 4];
            float4 b0v = *(const float4*)&Ws[kk][wc * 64 + lj * 8];
            float4 b1v = *(const float4*)&Ws[kk][wc * 64 + lj * 8 + 4];
            float av[8] = {a0.x,a0.y,a0.z,a0.w,a1.x,a1.y,a1.z,a1.w};
            float bv[8] = {b0v.x,b0v.y,b0v.z,b0v.w,b1v.x,b1v.y,b1v.z,b1v.w};
            #pragma unroll
            for (int ri = 0; ri < 8; ++ri)
                #pragma unroll
                for (int rj = 0; rj < 8; ++rj)
                    acc[ri][rj] = fmaf(av[ri], bv[rj], acc[ri][rj]);
        }
    }

    const int nb = n0 + wc * 64 + lj * 8;
    float bv0[8];
    *(float4*)&bv0[0] = *(const float4*)&bias[nb];
    *(float4*)&bv0[4] = *(const float4*)&bias[nb + 4];
    #pragma unroll
    for (int ri = 0; ri < 8; ++ri) {
        int m = m0 + wr * 64 + li * 8 + ri;
        float o[8];
        #pragma unroll
        for (int rj = 0; rj < 8; ++rj) {
            float v = acc[ri][rj] + bv0[rj];   // same op order as R3: acc + bias
            if (GELU) v = 0.5f * v * (1.0f + erff(v * 0.7071067811865475f));
            o[rj] = v;
        }
        *(float4*)&C[(size_t)m * N + nb]     = make_float4(o[0],o[1],o[2],o[3]);
        *(float4*)&C[(size_t)m * N + nb + 4] = make_float4(o[4],o[5],o[6],o[7]);
    }
}

// ---------------------------------------------------------------------------
// APPROX scores via plain bf16 MFMA. Used only as a top-64 FILTER: the
// final selection is made on exactly-rescored fp32 values (topk_rescore),
// so ~1e-5 approx error here is harmless (rank-32 filter margin ~4.6e-3).
// Skeleton = round-2's reg-staged 2-barrier structure; epilogue/tile
// enumeration byte-identical to the verified fp32 scores_gemm.
// ---------------------------------------------------------------------------
__global__ __launch_bounds__(256, 2)
void scores_approx(const float* __restrict__ If, const float* __restrict__ Ff,
                   const float* __restrict__ lb, float* __restrict__ Sc, int h)
{
    __shared__ __align__(16) bf16_t AS[128][40];
    __shared__ __align__(16) bf16_t BS[128][40];
    const int t = threadIdx.x;

    int rt, jtl, jtg;
    {
        int id = blockIdx.x;
        if (h == 0) {
            if (id < 256) { rt = 16 + (id >> 4); jtl = id & 15; }
            else { int q = id - 256; rt = tri_row(q); jtl = q - rt * (rt + 1) / 2; }
            jtg = jtl;
        } else {
            int r = tri_row(id); rt = 16 + r;
            jtl = id - r * (r + 1) / 2; jtg = jtl + 16;
        }
    }
    const int b  = blockIdx.z;
    const int i0 = rt << 7, j0 = jtg << 7;
    const size_t bo = (size_t)b * SS * DD;
    const float* Ag = If + bo + (size_t)i0 * DD;
    const float* Bg = Ff + bo + (size_t)j0 * DD;

    const int r0 = t >> 2;          // staged row 0..63 (+64 for u=1)
    const int cb = (t & 3) * 8;     // k-offset within 32-elem chunk

    const int lane = t & 63, wav = t >> 6;
    const int wr = wav >> 1, wc = wav & 1;   // 2x2 waves over 64x64 regions
    const int lr = lane & 15;                // fragment row (A) / col (B)
    const int lk = lane >> 4;                // k-group 0..3

    f32x4 acc[4][4];
    #pragma unroll
    for (int i = 0; i < 4; ++i)
        #pragma unroll
        for (int j = 0; j < 4; ++j) {
            acc[i][j][0] = 0.f; acc[i][j][1] = 0.f;
            acc[i][j][2] = 0.f; acc[i][j][3] = 0.f;
        }

    float4 aF[4], bF[4];                     // prefetch regs
    #pragma unroll
    for (int u = 0; u < 2; ++u) {            // prologue: chunk 0 -> regs
        const float* ap = Ag + (size_t)(u * 64 + r0) * DD + cb;
        const float* bp = Bg + (size_t)(u * 64 + r0) * DD + cb;
        aF[2*u] = *(const float4*)ap;  aF[2*u+1] = *(const float4*)(ap + 4);
        bF[2*u] = *(const float4*)bp;  bF[2*u+1] = *(const float4*)(bp + 4);
    }

    for (int c = 0; c < 16; ++c) {
        __syncthreads();                     // prev chunk's reads done
        #pragma unroll
        for (int u = 0; u < 2; ++u) {        // cvt + regs -> LDS
            float va[8] = {aF[2*u].x, aF[2*u].y, aF[2*u].z, aF[2*u].w,
                           aF[2*u+1].x, aF[2*u+1].y, aF[2*u+1].z, aF[2*u+1].w};
            float vb[8] = {bF[2*u].x, bF[2*u].y, bF[2*u].z, bF[2*u].w,
                           bF[2*u+1].x, bF[2*u+1].y, bF[2*u+1].z, bF[2*u+1].w};
            bf16x8 av8, bv8;
            #pragma unroll
            for (int e = 0; e < 8; ++e) {
                av8[e] = (bf16_t)va[e];
                bv8[e] = (bf16_t)vb[e];
            }
            int rw = u * 64 + r0;
            *(bf16x8*)&AS[rw][cb] = av8;
            *(bf16x8*)&BS[rw][cb] = bv8;
        }
        __syncthreads();                     // LDS ready
        if (c + 1 < 16) {                    // prefetch next chunk
            int k0 = (c + 1) * 32;
            #pragma unroll
            for (int u = 0; u < 2; ++u) {
                const float* ap = Ag + (size_t)(u * 64 + r0) * DD + k0 + cb;
                const float* bp = Bg + (size_t)(u * 64 + r0) * DD + k0 + cb;
                aF[2*u] = *(const float4*)ap;  aF[2*u+1] = *(const float4*)(ap + 4);
                bF[2*u] = *(const float4*)bp;  bF[2*u+1] = *(const float4*)(bp + 4);
            }
        }
        bf16x8 bh[4];
        #pragma unroll
        for (int j = 0; j < 4; ++j)
            bh[j] = *(const bf16x8*)&BS[wc * 64 + j * 16 + lr][lk * 8];
        #pragma unroll
        for (int i = 0; i < 4; ++i) {
            bf16x8 ah = *(const bf16x8*)&AS[wr * 64 + i * 16 + lr][lk * 8];
            #pragma unroll
            for (int j = 0; j < 4; ++j)
                acc[i][j] = __builtin_amdgcn_mfma_f32_16x16x32_bf16(
                                ah, bh[j], acc[i][j], 0, 0, 0);
        }
    }

    // Epilogue: C/D layout col = lane&15, row = 4*(lane>>4)+reg (m89/m91).
    const bool farTile = (i0 - j0) >= 256;
    const float lb0 = lb[0];
    #pragma unroll
    for (int i = 0; i < 4; ++i) {
        #pragma unroll
        for (int j = 0; j < 4; ++j) {
            int gj    = j0 + wc * 64 + j * 16 + lr;
            int cbase = (jtl << 7) + wc * 64 + j * 16 + lr;
            #pragma unroll
            for (int rg = 0; rg < 4; ++rg) {
                int gi = i0 + wr * 64 + i * 16 + lk * 4 + rg;
                float v = acc[i][j][rg] * SCALE;
                if (farTile) v += lb0;
                else {
                    int rel = gj - gi;
                    int bi  = rel < -64 ? 0 : rel + 64;
                    v += lb[min(bi, 127)];
                    if (rel > 0) v = -INFINITY;
                }
                Sc[((size_t)b * SS + gi) * HALF + cbase] = v;
            }
        }
    }
}

// ---------------------------------------------------------------------------
// Top-k with exact rescore:
//   phase 1: top-64 on APPROX scores (superset filter, one cand per lane)
//   phase 2: exact fp32 rescore of each candidate — BITWISE the verified
//            round-0 chain: ascending-k fmaf dot, *SCALE, +lb[min(bi,127)],
//            rel>0 -> -inf
//   phase 3: exact top-32 by rank-count (tie-break: lower index)
//   phase 4: partial store / merge / softmax (unchanged, verified)
// Final output is bitwise identical to the round-0 kernel as long as the
// true top-32 lies within the approx top-64 (margin ~400 sigma).
// ---------------------------------------------------------------------------
__global__ __launch_bounds__(256)
void topk_rescore(const float* __restrict__ Sc,
                  const float* __restrict__ If, const float* __restrict__ Ff,
                  const float* __restrict__ lb,
                  const float* __restrict__ p0v_in, const int* __restrict__ p0j_in,
                  float* __restrict__ p0v_out, int* __restrict__ p0j_out,
                  float* __restrict__ out, int h)
{
    __shared__ float mv[4][64];
    __shared__ int   mj[4][64];
    __shared__ float sOv[4][32];
    __shared__ int   sOj[4][32];

    const int lane = threadIdx.x & 63;
    const int w    = threadIdx.x >> 6;
    const int wid  = blockIdx.x * 4 + w;
    int b, i;
    if (h == 0) { b = wid >> 12; i = wid & 4095; }
    else        { b = wid >> 11; i = HALF + (wid & 2047); }
    const int nv = (h == 0) ? min(i + 1, HALF) : (i + 1 - HALF);
    const size_t rb = ((size_t)b * SS + i) * HALF;
    const int l4 = lane * 4;

    float val[32];
    #pragma unroll
    for (int s = 0; s < 8; ++s) {
        int jb = s * 256 + l4;
        float4 f = make_float4(-INFINITY, -INFINITY, -INFINITY, -INFINITY);
        if (jb < nv) f = *(const float4*)&Sc[rb + jb];
        val[4*s+0] = (jb + 0 < nv) ? f.x : -INFINITY;
        val[4*s+1] = (jb + 1 < nv) ? f.y : -INFINITY;
        val[4*s+2] = (jb + 2 < nv) ? f.z : -INFINITY;
        val[4*s+3] = (jb + 3 < nv) ? f.w : -INFINITY;
    }

    // ---- phase 1: approx top-64 (one candidate per lane) ----
    unsigned dead = 0;
    float Lv; int Lj, Lc;
    auto localmax = [&]() {
        Lv = -INFINITY; Lj = 0x7fffffff; Lc = 0;
        #pragma unroll
        for (int c = 0; c < 32; ++c) {
            int jh = (c >> 2) * 256 + l4 + (c & 3);
            bool alive = !((dead >> c) & 1u);
            bool bet = alive && (val[c] > Lv || (val[c] == Lv && jh < Lj));
            if (bet) { Lv = val[c]; Lj = jh; Lc = c; }
        }
    };
    localmax();

    float selv = -INFINITY; int selj = h * HALF;
    for (int r = 0; r < KSEL; ++r) {
        float bv = Lv; int bj = Lj;
        #pragma unroll
        for (int m = 1; m < 64; m <<= 1) {
            float ov = __shfl_xor(bv, m, 64);
            int   oj = __shfl_xor(bj, m, 64);
            if (ov > bv || (ov == bv && oj < bj)) { bv = ov; bj = oj; }
        }
        if (lane == r) { selv = bv; selj = bj + h * HALF; }
        if (bj == Lj) { dead |= (1u << Lc); localmax(); }
    }
    // clamp pathological sentinel (bj==0x7fffffff can't occur: 2048 >= KSEL cands)
    selj = min(selj, h * HALF + HALF - 1);

    // ---- phase 2: exact rescore (bitwise round-0 chain) ----
    {
        const size_t bo = (size_t)b * SS * DD;
        const float* Irow = If + bo + (size_t)i * DD;
        const float* Frow = Ff + bo + (size_t)selj * DD;
        float acc = 0.f;
        #pragma unroll 4
        for (int k = 0; k < DD; k += 4) {
            float4 fi = *(const float4*)&Irow[k];
            float4 fj = *(const float4*)&Frow[k];
            acc = fmaf(fi.x, fj.x, acc);
            acc = fmaf(fi.y, fj.y, acc);
            acc = fmaf(fi.z, fj.z, acc);
            acc = fmaf(fi.w, fj.w, acc);
        }
        float v = acc * SCALE;
        int rel = selj - i;
        int bi  = rel < -64 ? 0 : rel + 64;
        v += lb[min(bi, 127)];
        if (rel > 0) v = -INFINITY;
        selv = v;
    }

    // ---- phase 3: exact top-32 of the 64 candidates ----
    mv[w][lane] = selv; mj[w][lane] = selj;
    __syncthreads();
    int rk = 0;
    #pragma unroll
    for (int f = 0; f < 64; ++f) {
        float fv = mv[w][f]; int fj = mj[w][f];
        rk += (fv > selv || (fv == selv && fj < selj)) ? 1 : 0;
    }
    if (rk < KTOP) { sOv[w][rk] = selv; sOj[w][rk] = selj; }
    __syncthreads();
    if (lane < KTOP) { selv = sOv[w][lane]; selj = sOj[w][lane]; }

    // ---- phase 4: partial store / merge / softmax (verified, unchanged) ----
    if (h == 0 && i >= HALF) {
        if (lane < KTOP) {
            size_t pb = ((size_t)b * HALF + (i - HALF)) * KTOP + lane;
            p0v_out[pb] = selv; p0j_out[pb] = selj;
        }
        return;
    }

    if (h == 1) {
        float p0v = 0.f; int p0j = 0;
        __syncthreads();   // phase-3 reads of mv done before merge overwrites
        if (lane < KTOP) {
            size_t pb = ((size_t)b * HALF + (i - HALF)) * KTOP + lane;
            p0v = p0v_in[pb]; p0j = p0j_in[pb];
            mv[w][lane] = p0v;         mj[w][lane] = p0j;
            mv[w][KTOP + lane] = selv; mj[w][KTOP + lane] = selj;
        }
        __syncthreads();
        int r0 = 0, r1 = 0;
        if (lane < KTOP) {
            for (int f = 0; f < 64; ++f) {
                float fv = mv[w][f]; int fj = mj[w][f];
                r0 += (fv > p0v || (fv == p0v && fj < p0j)) ? 1 : 0;
                r1 += (fv > selv || (fv == selv && fj < selj)) ? 1 : 0;
            }
        }
        __syncthreads();
        if (lane < KTOP) {
            if (r0 < KTOP) { sOv[w][r0] = p0v;  sOj[w][r0] = p0j;  }
            if (r1 < KTOP) { sOv[w][r1] = selv; sOj[w][r1] = selj; }
        }
        __syncthreads();
        if (lane < KTOP) { selv = sOv[w][lane]; selj = sOj[w][lane]; }
    }

    float mx = __shfl(selv, 0, 64);
    float e  = (lane < KTOP) ? expf(selv - mx) : 0.f;
    float sum = e;
    #pragma unroll
    for (int m = 1; m < 64; m <<= 1) sum += __shfl_xor(sum, m, 64);
    float invs = 1.0f / sum;
    if (lane < KTOP) {
        size_t ob = ((size_t)b * SS + i) * KTOP + lane;
        out[ob] = (float)selj;
        out[(size_t)BB * SS * KTOP + ob] = e * invs;
    }
}

// ---------------------------------------------------------------------------
extern "C" void kernel_launch(void* const* d_in, const int* in_sizes, int n_in,
                              void* d_out, int out_size, void* d_ws, size_t ws_size,
                              hipStream_t stream)
{
    const float* x   = (const float*)d_in[0];
    const float* Wi1 = (const float*)d_in[1];
    const float* bi1 = (const float*)d_in[2];
    const float* Wi2 = (const float*)d_in[3];
    const float* bi2 = (const float*)d_in[4];
    const float* Wf1 = (const float*)d_in[5];
    const float* bf1 = (const float*)d_in[6];
    const float* Wf2 = (const float*)d_in[7];
    const float* bf2 = (const float*)d_in[8];
    const float* lb  = (const float*)d_in[9];
    // d_in[10..13] = adaptive-k MLP (unused for outputs); d_in[14] = mask (all ones)

    const size_t NF = (size_t)BB * SS * DD;          // 4,194,304 floats
    float* ws       = (float*)d_ws;                  // total ~109 MB (R3-verified)
    float* intents  = ws;                            // NF
    float* features = ws + NF;                       // NF
    float* part0v   = ws + 2 * NF;
    int*   part0j   = (int*)(part0v + (size_t)BB * HALF * KTOP);
    float* Sc       = ws + 2 * NF + NF / 2;          // BB*SS*HALF floats (67 MB)
    float* Hi       = Sc;                            // MLP scratch inside Sc area
    float* Hf       = Sc + NF / 2;                   // (used before Sc is written)

    // MLP1 pair (x@W1+b1, GELU): z=0 -> intents path, z=1 -> features path
    gemm128<true ><<<dim3(DH / 128, 64, 2), 256, 0, stream>>>(
        x, x, Wi1, Wf1, bi1, bf1, Hi, Hf, DH, DD);
    // MLP2 pair (H@W2+b2)
    gemm128<false><<<dim3(DD / 128, 64, 2), 256, 0, stream>>>(
        Hi, Hf, Wi2, Wf2, bi2, bf2, intents, features, DD, DH);

    // half 0: j in [0,2048); live tiles only (256 rect + 136 tri)
    scores_approx<<<dim3(392, 1, BB), 256, 0, stream>>>(intents, features, lb, Sc, 0);
    topk_rescore<<<(BB * SS) / 4, 256, 0, stream>>>(Sc, intents, features, lb,
                                                    part0v, part0j, part0v, part0j,
                                                    (float*)d_out, 0);
    // half 1: j in [2048,4096), rows >= 2048; 136 tri tiles
    scores_approx<<<dim3(136, 1, BB), 256, 0, stream>>>(intents, features, lb, Sc, 1);
    topk_rescore<<<(BB * HALF) / 4, 256, 0, stream>>>(Sc, intents, features, lb,
                                                      part0v, part0j, part0v, part0j,
                                                      (float*)d_out, 1);
}

// Round 5
// 559.142 us; speedup vs baseline: 1.8228x; 1.8228x over previous
//
#include <hip/hip_runtime.h>
#include <math.h>

// Problem constants (B=2, S=4096, D=512, MAXC=32, BIAS_LEN=128, TEMP=1)
#define BB   2
#define SS   4096
#define DD   512
#define DH   256      // D/2
#define KTOP 32
#define KSEL 64       // candidate slots (one per lane)
#define TGT  48       // threshold target: count(key >= T) >= TGT (margin 16 ranks)
#define HALF 2048     // j processed in two halves to bound workspace
#define SCALE 0.044194173824159216f   // 1/sqrt(512)

typedef __bf16 bf16_t;
typedef bf16_t bf16x8 __attribute__((ext_vector_type(8)));
typedef float  f32x4  __attribute__((ext_vector_type(4)));

// decode row of triangular tile list: q in [0, r_max*(r_max+1)/2)
__device__ __forceinline__ int tri_row(int q) {
    int r = (int)((sqrtf(8.0f * q + 1.0f) - 1.0f) * 0.5f);
    while ((r + 1) * (r + 2) / 2 <= q) ++r;
    while (r * (r + 1) / 2 > q) --r;
    return r;
}

// ---------------------------------------------------------------------------
// MLP GEMM v8 (unchanged, verified): 128x128 tile, 8x8 micro, FP32 VALU.
// ---------------------------------------------------------------------------
template<bool GELU>
__global__ __launch_bounds__(256)
void gemm128(const float* __restrict__ A0, const float* __restrict__ A1,
             const float* __restrict__ W0, const float* __restrict__ W1,
             const float* __restrict__ b0, const float* __restrict__ b1,
             float* __restrict__ C0, float* __restrict__ C1,
             int N, int K)
{
    __shared__ float As[32][132];   // [k][m]
    __shared__ float Ws[32][132];   // [k][n]
    const int t = threadIdx.x;
    const int z = blockIdx.z;
    const float* A    = z ? A1 : A0;
    const float* W    = z ? W1 : W0;
    const float* bias = z ? b1 : b0;
    float*       C    = z ? C1 : C0;
    const int n0 = blockIdx.x * 128;
    const int m0 = blockIdx.y * 128;

    const int kq = t & 7;          // A stager: k-quad within chunk
    const int rr = t >> 3;         // A stager: row 0..31 (+u*32)
    const int wkr = t >> 3;        // W stager: k-row 0..31
    const int wnc = (t & 7) * 16;  // W stager: col group (16 cols = 4 float4)
    const float* Ab = A + (size_t)m0 * K;
    const float* Wb = W + (size_t)0 * N + n0;

    const int lane = t & 63, wav = t >> 6;
    const int wr = wav >> 1, wc = wav & 1;     // wave 2x2 over 64x64 regions
    const int li = lane >> 3, lj = lane & 7;   // 8x8 lane grid

    float acc[8][8] = {};
    float4 aR[4], wR[4];
    #pragma unroll
    for (int u = 0; u < 4; ++u) {              // prologue: chunk 0 -> regs
        int r = u * 32 + rr;
        aR[u] = *(const float4*)&Ab[(size_t)r * K + 4 * kq];
        wR[u] = *(const float4*)&Wb[(size_t)wkr * N + wnc + 4 * u];
    }
    const int nch = K >> 5;
    for (int c = 0; c < nch; ++c) {
        __syncthreads();
        #pragma unroll
        for (int u = 0; u < 4; ++u) {          // regs -> LDS
            int r = u * 32 + rr;
            As[4*kq+0][r] = aR[u].x; As[4*kq+1][r] = aR[u].y;
            As[4*kq+2][r] = aR[u].z; As[4*kq+3][r] = aR[u].w;
            *(float4*)&Ws[wkr][wnc + 4 * u] = wR[u];
        }
        __syncthreads();
        if (c + 1 < nch) {                     // prefetch next chunk
            int k0 = (c + 1) * 32;
            #pragma unroll
            for (int u = 0; u < 4; ++u) {
                int r = u * 32 + rr;
                aR[u] = *(const float4*)&Ab[(size_t)r * K + k0 + 4 * kq];
                wR[u] = *(const float4*)&Wb[(size_t)(k0 + wkr) * N + wnc + 4 * u];
            }
        }
        #pragma unroll
        for (int kk = 0; kk < 32; ++kk) {      // conflict-free: 8 addrs x 8-bcast
            float4 a0 = *(const float4*)&As[kk][wr * 64 + li * 8];
            float4 a1 = *(const float4*)&As[kk][wr * 64 + li * 8 + 4];
            float4 b0v = *(const float4*)&Ws[kk][wc * 64 + lj * 8];
            float4 b1v = *(const float4*)&Ws[kk][wc * 64 + lj * 8 + 4];
            float av[8] = {a0.x,a0.y,a0.z,a0.w,a1.x,a1.y,a1.z,a1.w};
            float bv[8] = {b0v.x,b0v.y,b0v.z,b0v.w,b1v.x,b1v.y,b1v.z,b1v.w};
            #pragma unroll
            for (int ri = 0; ri < 8; ++ri)
                #pragma unroll
                for (int rj = 0; rj < 8; ++rj)
                    acc[ri][rj] = fmaf(av[ri], bv[rj], acc[ri][rj]);
        }
    }

    const int nb = n0 + wc * 64 + lj * 8;
    float bv0[8];
    *(float4*)&bv0[0] = *(const float4*)&bias[nb];
    *(float4*)&bv0[4] = *(const float4*)&bias[nb + 4];
    #pragma unroll
    for (int ri = 0; ri < 8; ++ri) {
        int m = m0 + wr * 64 + li * 8 + ri;
        float o[8];
        #pragma unroll
        for (int rj = 0; rj < 8; ++rj) {
            float v = acc[ri][rj] + bv0[rj];   // same op order as R3: acc + bias
            if (GELU) v = 0.5f * v * (1.0f + erff(v * 0.7071067811865475f));
            o[rj] = v;
        }
        *(float4*)&C[(size_t)m * N + nb]     = make_float4(o[0],o[1],o[2],o[3]);
        *(float4*)&C[(size_t)m * N + nb + 4] = make_float4(o[4],o[5],o[6],o[7]);
    }
}

// ---------------------------------------------------------------------------
// APPROX scores via plain bf16 MFMA (byte-identical to round-4 PASSING
// version). Used only as a candidate FILTER: final selection is made on
// exactly-rescored fp32 values in topk_rescore.
// ---------------------------------------------------------------------------
__global__ __launch_bounds__(256, 2)
void scores_approx(const float* __restrict__ If, const float* __restrict__ Ff,
                   const float* __restrict__ lb, float* __restrict__ Sc, int h)
{
    __shared__ __align__(16) bf16_t AS[128][40];
    __shared__ __align__(16) bf16_t BS[128][40];
    const int t = threadIdx.x;

    int rt, jtl, jtg;
    {
        int id = blockIdx.x;
        if (h == 0) {
            if (id < 256) { rt = 16 + (id >> 4); jtl = id & 15; }
            else { int q = id - 256; rt = tri_row(q); jtl = q - rt * (rt + 1) / 2; }
            jtg = jtl;
        } else {
            int r = tri_row(id); rt = 16 + r;
            jtl = id - r * (r + 1) / 2; jtg = jtl + 16;
        }
    }
    const int b  = blockIdx.z;
    const int i0 = rt << 7, j0 = jtg << 7;
    const size_t bo = (size_t)b * SS * DD;
    const float* Ag = If + bo + (size_t)i0 * DD;
    const float* Bg = Ff + bo + (size_t)j0 * DD;

    const int r0 = t >> 2;          // staged row 0..63 (+64 for u=1)
    const int cb = (t & 3) * 8;     // k-offset within 32-elem chunk

    const int lane = t & 63, wav = t >> 6;
    const int wr = wav >> 1, wc = wav & 1;   // 2x2 waves over 64x64 regions
    const int lr = lane & 15;                // fragment row (A) / col (B)
    const int lk = lane >> 4;                // k-group 0..3

    f32x4 acc[4][4];
    #pragma unroll
    for (int i = 0; i < 4; ++i)
        #pragma unroll
        for (int j = 0; j < 4; ++j) {
            acc[i][j][0] = 0.f; acc[i][j][1] = 0.f;
            acc[i][j][2] = 0.f; acc[i][j][3] = 0.f;
        }

    float4 aF[4], bF[4];                     // prefetch regs
    #pragma unroll
    for (int u = 0; u < 2; ++u) {            // prologue: chunk 0 -> regs
        const float* ap = Ag + (size_t)(u * 64 + r0) * DD + cb;
        const float* bp = Bg + (size_t)(u * 64 + r0) * DD + cb;
        aF[2*u] = *(const float4*)ap;  aF[2*u+1] = *(const float4*)(ap + 4);
        bF[2*u] = *(const float4*)bp;  bF[2*u+1] = *(const float4*)(bp + 4);
    }

    for (int c = 0; c < 16; ++c) {
        __syncthreads();                     // prev chunk's reads done
        #pragma unroll
        for (int u = 0; u < 2; ++u) {        // cvt + regs -> LDS
            float va[8] = {aF[2*u].x, aF[2*u].y, aF[2*u].z, aF[2*u].w,
                           aF[2*u+1].x, aF[2*u+1].y, aF[2*u+1].z, aF[2*u+1].w};
            float vb[8] = {bF[2*u].x, bF[2*u].y, bF[2*u].z, bF[2*u].w,
                           bF[2*u+1].x, bF[2*u+1].y, bF[2*u+1].z, bF[2*u+1].w};
            bf16x8 av8, bv8;
            #pragma unroll
            for (int e = 0; e < 8; ++e) {
                av8[e] = (bf16_t)va[e];
                bv8[e] = (bf16_t)vb[e];
            }
            int rw = u * 64 + r0;
            *(bf16x8*)&AS[rw][cb] = av8;
            *(bf16x8*)&BS[rw][cb] = bv8;
        }
        __syncthreads();                     // LDS ready
        if (c + 1 < 16) {                    // prefetch next chunk
            int k0 = (c + 1) * 32;
            #pragma unroll
            for (int u = 0; u < 2; ++u) {
                const float* ap = Ag + (size_t)(u * 64 + r0) * DD + k0 + cb;
                const float* bp = Bg + (size_t)(u * 64 + r0) * DD + k0 + cb;
                aF[2*u] = *(const float4*)ap;  aF[2*u+1] = *(const float4*)(ap + 4);
                bF[2*u] = *(const float4*)bp;  bF[2*u+1] = *(const float4*)(bp + 4);
            }
        }
        bf16x8 bh[4];
        #pragma unroll
        for (int j = 0; j < 4; ++j)
            bh[j] = *(const bf16x8*)&BS[wc * 64 + j * 16 + lr][lk * 8];
        #pragma unroll
        for (int i = 0; i < 4; ++i) {
            bf16x8 ah = *(const bf16x8*)&AS[wr * 64 + i * 16 + lr][lk * 8];
            #pragma unroll
            for (int j = 0; j < 4; ++j)
                acc[i][j] = __builtin_amdgcn_mfma_f32_16x16x32_bf16(
                                ah, bh[j], acc[i][j], 0, 0, 0);
        }
    }

    // Epilogue: C/D layout col = lane&15, row = 4*(lane>>4)+reg (m89/m91).
    const bool farTile = (i0 - j0) >= 256;
    const float lb0 = lb[0];
    #pragma unroll
    for (int i = 0; i < 4; ++i) {
        #pragma unroll
        for (int j = 0; j < 4; ++j) {
            int gj    = j0 + wc * 64 + j * 16 + lr;
            int cbase = (jtl << 7) + wc * 64 + j * 16 + lr;
            #pragma unroll
            for (int rg = 0; rg < 4; ++rg) {
                int gi = i0 + wr * 64 + i * 16 + lk * 4 + rg;
                float v = acc[i][j][rg] * SCALE;
                if (farTile) v += lb0;
                else {
                    int rel = gj - gi;
                    int bi  = rel < -64 ? 0 : rel + 64;
                    v += lb[min(bi, 127)];
                    if (rel > 0) v = -INFINITY;
                }
                Sc[((size_t)b * SS + gi) * HALF + cbase] = v;
            }
        }
    }
}

// ---------------------------------------------------------------------------
// Top-k with exact rescore. Round-5 change: phase 1 (candidate finding)
// replaced by radix threshold search + ballot compaction.
//   phase 1: monotone uint keys; MSB-descend to largest T with
//            count(key>=T) >= TGT(48), early-exit when count in [48,64];
//            ballot-prefix compact survivor indices (cap 64).
//            Margin: a true-top-32 miss needs >=17-rank approx slippage
//            (~1.2e-3) vs ~2e-5 approx error -> ~60 sigma. Rows with
//            nv<=64 take a direct path (first 64 indices of the half),
//            reproducing causal -inf tie ordering exactly.
//   phase 2: exact fp32 rescore — BITWISE the verified round-0 chain.
//   phase 3: exact top-32 rank-count (tie-break: lower index). [verified R4]
//   phase 4: partial store / merge / softmax. [verified R4]
// ---------------------------------------------------------------------------
__global__ __launch_bounds__(256)
void topk_rescore(const float* __restrict__ Sc,
                  const float* __restrict__ If, const float* __restrict__ Ff,
                  const float* __restrict__ lb,
                  const float* __restrict__ p0v_in, const int* __restrict__ p0j_in,
                  float* __restrict__ p0v_out, int* __restrict__ p0j_out,
                  float* __restrict__ out, int h)
{
    __shared__ float mv[4][64];
    __shared__ int   mj[4][64];
    __shared__ float sOv[4][32];
    __shared__ int   sOj[4][32];
    __shared__ int   sCand[4][64];

    const int lane = threadIdx.x & 63;
    const int w    = threadIdx.x >> 6;
    const int wid  = blockIdx.x * 4 + w;
    int b, i;
    if (h == 0) { b = wid >> 12; i = wid & 4095; }
    else        { b = wid >> 11; i = HALF + (wid & 2047); }
    const int nv = (h == 0) ? min(i + 1, HALF) : (i + 1 - HALF);  // == finite count
    const size_t rb = ((size_t)b * SS + i) * HALF;
    const int l4 = lane * 4;

    int n = KSEL;
    int selj;
    if (nv <= KSEL) {
        // direct path: candidates = first 64 indices of this half. Includes
        // causal -inf entries; exact rescore + index tie-break reproduces
        // the reference's (finite desc, then -inf by ascending j) ordering.
        selj = h * HALF + lane;
    } else {
        // ---- phase 1a: load scores as monotone-sortable uint keys ----
        unsigned key[32];
        #pragma unroll
        for (int s = 0; s < 8; ++s) {
            int jb = s * 256 + l4;
            float4 f = make_float4(-INFINITY, -INFINITY, -INFINITY, -INFINITY);
            if (jb < nv) f = *(const float4*)&Sc[rb + jb];
            float vv[4] = {f.x, f.y, f.z, f.w};
            #pragma unroll
            for (int q = 0; q < 4; ++q) {
                unsigned ub = __float_as_uint(vv[q]);
                unsigned k  = (ub & 0x80000000u) ? ~ub : (ub | 0x80000000u);
                key[4*s+q] = ((jb + q) < nv) ? k : 0u;   // pads sort below -inf
            }
        }
        // ---- phase 1b: radix-descend threshold (wave-uniform control) ----
        unsigned cur = 0u;
        int csel = HALF;   // count(key >= cur); cur=0 -> all
        for (int bit = 31; bit >= 0 && csel > KSEL; --bit) {
            unsigned test = cur | (1u << bit);
            int cl = 0;
            #pragma unroll
            for (int c = 0; c < 32; ++c) cl += (key[c] >= test) ? 1 : 0;
            #pragma unroll
            for (int m = 1; m < 64; m <<= 1) cl += __shfl_xor(cl, m, 64);
            if (cl >= TGT) { cur = test; csel = cl; }
        }
        // nv >= 65 guarantees >= 48 finite values, so cur > key(-inf):
        // all survivors are causally valid (finite under exact rescore too).
        // ---- phase 1c: ballot-prefix compaction (cap 64, intra-wave LDS) ----
        int base = 0;
        #pragma unroll
        for (int c = 0; c < 32; ++c) {
            bool surv = key[c] >= cur;
            unsigned long long mm = __ballot(surv);
            if (surv) {
                int pos = base + (int)__popcll(mm & ((1ull << lane) - 1ull));
                if (pos < KSEL)
                    sCand[w][pos] = (c >> 2) * 256 + l4 + (c & 3) + h * HALF;
            }
            base += (int)__popcll(mm);
        }
        n = min(base, KSEL);                 // n in [48, 64]
        selj = (lane < n) ? sCand[w][lane] : (h * HALF);
    }

    // ---- phase 2: exact rescore (bitwise round-0 chain) ----
    float selv;
    {
        const size_t bo = (size_t)b * SS * DD;
        const float* Irow = If + bo + (size_t)i * DD;
        const float* Frow = Ff + bo + (size_t)selj * DD;
        float acc = 0.f;
        #pragma unroll 4
        for (int k = 0; k < DD; k += 4) {
            float4 fi = *(const float4*)&Irow[k];
            float4 fj = *(const float4*)&Frow[k];
            acc = fmaf(fi.x, fj.x, acc);
            acc = fmaf(fi.y, fj.y, acc);
            acc = fmaf(fi.z, fj.z, acc);
            acc = fmaf(fi.w, fj.w, acc);
        }
        float v = acc * SCALE;
        int rel = selj - i;
        int bi  = rel < -64 ? 0 : rel + 64;
        v += lb[min(bi, 127)];
        if (rel > 0) v = -INFINITY;
        selv = v;
    }
    if (lane >= n) selv = -INFINITY;   // pad lanes (rank >= 48 > 32: inert)

    // ---- phase 3: exact top-32 of the candidates (verified R4) ----
    mv[w][lane] = selv; mj[w][lane] = selj;
    __syncthreads();
    int rk = 0;
    #pragma unroll
    for (int f = 0; f < 64; ++f) {
        float fv = mv[w][f]; int fj = mj[w][f];
        rk += (fv > selv || (fv == selv && fj < selj)) ? 1 : 0;
    }
    if (rk < KTOP) { sOv[w][rk] = selv; sOj[w][rk] = selj; }
    __syncthreads();
    if (lane < KTOP) { selv = sOv[w][lane]; selj = sOj[w][lane]; }

    // ---- phase 4: partial store / merge / softmax (verified R4) ----
    if (h == 0 && i >= HALF) {
        if (lane < KTOP) {
            size_t pb = ((size_t)b * HALF + (i - HALF)) * KTOP + lane;
            p0v_out[pb] = selv; p0j_out[pb] = selj;
        }
        return;
    }

    if (h == 1) {
        float p0v = 0.f; int p0j = 0;
        __syncthreads();   // phase-3 reads of mv done before merge overwrites
        if (lane < KTOP) {
            size_t pb = ((size_t)b * HALF + (i - HALF)) * KTOP + lane;
            p0v = p0v_in[pb]; p0j = p0j_in[pb];
            mv[w][lane] = p0v;         mj[w][lane] = p0j;
            mv[w][KTOP + lane] = selv; mj[w][KTOP + lane] = selj;
        }
        __syncthreads();
        int r0 = 0, r1 = 0;
        if (lane < KTOP) {
            for (int f = 0; f < 64; ++f) {
                float fv = mv[w][f]; int fj = mj[w][f];
                r0 += (fv > p0v || (fv == p0v && fj < p0j)) ? 1 : 0;
                r1 += (fv > selv || (fv == selv && fj < selj)) ? 1 : 0;
            }
        }
        __syncthreads();
        if (lane < KTOP) {
            if (r0 < KTOP) { sOv[w][r0] = p0v;  sOj[w][r0] = p0j;  }
            if (r1 < KTOP) { sOv[w][r1] = selv; sOj[w][r1] = selj; }
        }
        __syncthreads();
        if (lane < KTOP) { selv = sOv[w][lane]; selj = sOj[w][lane]; }
    }

    float mx = __shfl(selv, 0, 64);
    float e  = (lane < KTOP) ? expf(selv - mx) : 0.f;
    float sum = e;
    #pragma unroll
    for (int m = 1; m < 64; m <<= 1) sum += __shfl_xor(sum, m, 64);
    float invs = 1.0f / sum;
    if (lane < KTOP) {
        size_t ob = ((size_t)b * SS + i) * KTOP + lane;
        out[ob] = (float)selj;
        out[(size_t)BB * SS * KTOP + ob] = e * invs;
    }
}

// ---------------------------------------------------------------------------
extern "C" void kernel_launch(void* const* d_in, const int* in_sizes, int n_in,
                              void* d_out, int out_size, void* d_ws, size_t ws_size,
                              hipStream_t stream)
{
    const float* x   = (const float*)d_in[0];
    const float* Wi1 = (const float*)d_in[1];
    const float* bi1 = (const float*)d_in[2];
    const float* Wi2 = (const float*)d_in[3];
    const float* bi2 = (const float*)d_in[4];
    const float* Wf1 = (const float*)d_in[5];
    const float* bf1 = (const float*)d_in[6];
    const float* Wf2 = (const float*)d_in[7];
    const float* bf2 = (const float*)d_in[8];
    const float* lb  = (const float*)d_in[9];
    // d_in[10..13] = adaptive-k MLP (unused for outputs); d_in[14] = mask (all ones)

    const size_t NF = (size_t)BB * SS * DD;          // 4,194,304 floats
    float* ws       = (float*)d_ws;                  // total ~109 MB (R3-verified)
    float* intents  = ws;                            // NF
    float* features = ws + NF;                       // NF
    float* part0v   = ws + 2 * NF;
    int*   part0j   = (int*)(part0v + (size_t)BB * HALF * KTOP);
    float* Sc       = ws + 2 * NF + NF / 2;          // BB*SS*HALF floats (67 MB)
    float* Hi       = Sc;                            // MLP scratch inside Sc area
    float* Hf       = Sc + NF / 2;                   // (used before Sc is written)

    // MLP1 pair (x@W1+b1, GELU): z=0 -> intents path, z=1 -> features path
    gemm128<true ><<<dim3(DH / 128, 64, 2), 256, 0, stream>>>(
        x, x, Wi1, Wf1, bi1, bf1, Hi, Hf, DH, DD);
    // MLP2 pair (H@W2+b2)
    gemm128<false><<<dim3(DD / 128, 64, 2), 256, 0, stream>>>(
        Hi, Hf, Wi2, Wf2, bi2, bf2, intents, features, DD, DH);

    // half 0: j in [0,2048); live tiles only (256 rect + 136 tri)
    scores_approx<<<dim3(392, 1, BB), 256, 0, stream>>>(intents, features, lb, Sc, 0);
    topk_rescore<<<(BB * SS) / 4, 256, 0, stream>>>(Sc, intents, features, lb,
                                                    part0v, part0j, part0v, part0j,
                                                    (float*)d_out, 0);
    // half 1: j in [2048,4096), rows >= 2048; 136 tri tiles
    scores_approx<<<dim3(136, 1, BB), 256, 0, stream>>>(intents, features, lb, Sc, 1);
    topk_rescore<<<(BB * HALF) / 4, 256, 0, stream>>>(Sc, intents, features, lb,
                                                      part0v, part0j, part0v, part0j,
                                                      (float*)d_out, 1);
}

// Round 7
// 538.361 us; speedup vs baseline: 1.8932x; 1.0386x over previous
//
#include <hip/hip_runtime.h>
#include <math.h>

// Problem constants (B=2, S=4096, D=512, MAXC=32, BIAS_LEN=128, TEMP=1)
#define BB   2
#define SS   4096
#define DD   512
#define DH   256      // D/2
#define KTOP 32
#define KSEL 64       // candidate slots (one per lane)
#define TGT  48       // threshold target: count(key >= T) >= TGT (margin 16 ranks)
#define HALF 2048     // j processed in two halves to bound workspace
#define SCALE 0.044194173824159216f   // 1/sqrt(512)

typedef __bf16 bf16_t;
typedef bf16_t bf16x8 __attribute__((ext_vector_type(8)));
typedef float  f32x4  __attribute__((ext_vector_type(4)));

// decode row of triangular tile list: q in [0, r_max*(r_max+1)/2)
__device__ __forceinline__ int tri_row(int q) {
    int r = (int)((sqrtf(8.0f * q + 1.0f) - 1.0f) * 0.5f);
    while ((r + 1) * (r + 2) / 2 <= q) ++r;
    while (r * (r + 1) / 2 > q) --r;
    return r;
}

// tile-id decode shared by both scores kernels (verified R0..R5)
__device__ __forceinline__ void decode_tile(int id, int h, int& rt, int& jtl, int& jtg) {
    if (h == 0) {
        if (id < 256) { rt = 16 + (id >> 4); jtl = id & 15; }
        else { int q = id - 256; rt = tri_row(q); jtl = q - rt * (rt + 1) / 2; }
        jtg = jtl;
    } else {
        int r = tri_row(id); rt = 16 + r;
        jtl = id - r * (r + 1) / 2; jtg = jtl + 16;
    }
}

// ---------------------------------------------------------------------------
// MLP GEMM v8 (unchanged, verified): 128x128 tile, 8x8 micro, FP32 VALU.
// ---------------------------------------------------------------------------
template<bool GELU>
__global__ __launch_bounds__(256)
void gemm128(const float* __restrict__ A0, const float* __restrict__ A1,
             const float* __restrict__ W0, const float* __restrict__ W1,
             const float* __restrict__ b0, const float* __restrict__ b1,
             float* __restrict__ C0, float* __restrict__ C1,
             int N, int K)
{
    __shared__ float As[32][132];   // [k][m]
    __shared__ float Ws[32][132];   // [k][n]
    const int t = threadIdx.x;
    const int z = blockIdx.z;
    const float* A    = z ? A1 : A0;
    const float* W    = z ? W1 : W0;
    const float* bias = z ? b1 : b0;
    float*       C    = z ? C1 : C0;
    const int n0 = blockIdx.x * 128;
    const int m0 = blockIdx.y * 128;

    const int kq = t & 7;          // A stager: k-quad within chunk
    const int rr = t >> 3;         // A stager: row 0..31 (+u*32)
    const int wkr = t >> 3;        // W stager: k-row 0..31
    const int wnc = (t & 7) * 16;  // W stager: col group (16 cols = 4 float4)
    const float* Ab = A + (size_t)m0 * K;
    const float* Wb = W + (size_t)0 * N + n0;

    const int lane = t & 63, wav = t >> 6;
    const int wr = wav >> 1, wc = wav & 1;     // wave 2x2 over 64x64 regions
    const int li = lane >> 3, lj = lane & 7;   // 8x8 lane grid

    float acc[8][8] = {};
    float4 aR[4], wR[4];
    #pragma unroll
    for (int u = 0; u < 4; ++u) {              // prologue: chunk 0 -> regs
        int r = u * 32 + rr;
        aR[u] = *(const float4*)&Ab[(size_t)r * K + 4 * kq];
        wR[u] = *(const float4*)&Wb[(size_t)wkr * N + wnc + 4 * u];
    }
    const int nch = K >> 5;
    for (int c = 0; c < nch; ++c) {
        __syncthreads();
        #pragma unroll
        for (int u = 0; u < 4; ++u) {          // regs -> LDS
            int r = u * 32 + rr;
            As[4*kq+0][r] = aR[u].x; As[4*kq+1][r] = aR[u].y;
            As[4*kq+2][r] = aR[u].z; As[4*kq+3][r] = aR[u].w;
            *(float4*)&Ws[wkr][wnc + 4 * u] = wR[u];
        }
        __syncthreads();
        if (c + 1 < nch) {                     // prefetch next chunk
            int k0 = (c + 1) * 32;
            #pragma unroll
            for (int u = 0; u < 4; ++u) {
                int r = u * 32 + rr;
                aR[u] = *(const float4*)&Ab[(size_t)r * K + k0 + 4 * kq];
                wR[u] = *(const float4*)&Wb[(size_t)(k0 + wkr) * N + wnc + 4 * u];
            }
        }
        #pragma unroll
        for (int kk = 0; kk < 32; ++kk) {      // conflict-free: 8 addrs x 8-bcast
            float4 a0 = *(const float4*)&As[kk][wr * 64 + li * 8];
            float4 a1 = *(const float4*)&As[kk][wr * 64 + li * 8 + 4];
            float4 b0v = *(const float4*)&Ws[kk][wc * 64 + lj * 8];
            float4 b1v = *(const float4*)&Ws[kk][wc * 64 + lj * 8 + 4];
            float av[8] = {a0.x,a0.y,a0.z,a0.w,a1.x,a1.y,a1.z,a1.w};
            float bv[8] = {b0v.x,b0v.y,b0v.z,b0v.w,b1v.x,b1v.y,b1v.z,b1v.w};
            #pragma unroll
            for (int ri = 0; ri < 8; ++ri)
                #pragma unroll
                for (int rj = 0; rj < 8; ++rj)
                    acc[ri][rj] = fmaf(av[ri], bv[rj], acc[ri][rj]);
        }
    }

    const int nb = n0 + wc * 64 + lj * 8;
    float bv0[8];
    *(float4*)&bv0[0] = *(const float4*)&bias[nb];
    *(float4*)&bv0[4] = *(const float4*)&bias[nb + 4];
    #pragma unroll
    for (int ri = 0; ri < 8; ++ri) {
        int m = m0 + wr * 64 + li * 8 + ri;
        float o[8];
        #pragma unroll
        for (int rj = 0; rj < 8; ++rj) {
            float v = acc[ri][rj] + bv0[rj];   // same op order as R3: acc + bias
            if (GELU) v = 0.5f * v * (1.0f + erff(v * 0.7071067811865475f));
            o[rj] = v;
        }
        *(float4*)&C[(size_t)m * N + nb]     = make_float4(o[0],o[1],o[2],o[3]);
        *(float4*)&C[(size_t)m * N + nb + 4] = make_float4(o[4],o[5],o[6],o[7]);
    }
}

// ---------------------------------------------------------------------------
// fp32 -> bf16 copy (RNE cast, identical values to the in-kernel cvt).
// ---------------------------------------------------------------------------
__global__ __launch_bounds__(256)
void cvt_bf16(const float* __restrict__ src, bf16_t* __restrict__ dst)
{
    size_t idx = ((size_t)blockIdx.x * 256 + threadIdx.x) * 8;
    float4 f0 = *(const float4*)&src[idx];
    float4 f1 = *(const float4*)&src[idx + 4];
    float v[8] = {f0.x, f0.y, f0.z, f0.w, f1.x, f1.y, f1.z, f1.w};
    bf16x8 hv;
    #pragma unroll
    for (int j = 0; j < 8; ++j) hv[j] = (bf16_t)v[j];
    *(bf16x8*)&dst[idx] = hv;
}

// ---------------------------------------------------------------------------
// APPROX scores, NEW path: bf16 inputs + global_load_lds(16B) staging,
// m97 schedule (double-buffered [128][32] linear LDS, 1 barrier/chunk).
// MFMA sequence and epilogue are identical to scores_approx -> Sc bitwise
// identical. Staging correctness: round-1/round-2 forensic (identical
// absmax under different staging) shows this gload_lds pattern is sound.
// ---------------------------------------------------------------------------
__device__ __forceinline__ void stage_tile(const bf16_t* __restrict__ g,
                                           bf16_t* lds, int t, int k0)
{
    const int r0 = t >> 2;          // global row 0..63 (+64 for inst 1)
    const int cb = (t & 3) * 8;     // element offset within 32-elem slice
    const int wb = (t >> 6) * 512;  // wave-uniform LDS element base
    #pragma unroll
    for (int inst = 0; inst < 2; ++inst) {
        const bf16_t* gp = g + (size_t)(inst * 64 + r0) * DD + (k0 + cb);
        bf16_t* lp = lds + inst * 2048 + wb;   // + lane*8 elems added by HW
        __builtin_amdgcn_global_load_lds(
            (const __attribute__((address_space(1))) void*)gp,
            (__attribute__((address_space(3))) void*)lp, 16, 0, 0);
    }
}

__global__ __launch_bounds__(256, 2)
void scores_approx_g(const bf16_t* __restrict__ Ib, const bf16_t* __restrict__ Fb,
                     const float* __restrict__ lb, float* __restrict__ Sc, int h)
{
    __shared__ bf16_t As[2][128 * 32];
    __shared__ bf16_t Bs[2][128 * 32];
    const int t = threadIdx.x;

    int rt, jtl, jtg;
    decode_tile(blockIdx.x, h, rt, jtl, jtg);
    const int b  = blockIdx.z;
    const int i0 = rt << 7, j0 = jtg << 7;
    const size_t bo = (size_t)b * SS * DD;
    const bf16_t* Ag = Ib + bo + (size_t)i0 * DD;
    const bf16_t* Bg = Fb + bo + (size_t)j0 * DD;

    const int lane = t & 63, wav = t >> 6;
    const int wr = wav >> 1, wc = wav & 1;   // 2x2 waves over 64x64 regions
    const int lr = lane & 15;                // fragment row (A) / col (B)
    const int lk = lane >> 4;                // k-group 0..3

    f32x4 acc[4][4];
    #pragma unroll
    for (int i = 0; i < 4; ++i)
        #pragma unroll
        for (int j = 0; j < 4; ++j) {
            acc[i][j][0] = 0.f; acc[i][j][1] = 0.f;
            acc[i][j][2] = 0.f; acc[i][j][3] = 0.f;
        }

    stage_tile(Ag, &As[0][0], t, 0);
    stage_tile(Bg, &Bs[0][0], t, 0);
    for (int c = 0; c < 16; ++c) {
        __syncthreads();                 // drains vmcnt: buf[c&1] ready
        if (c + 1 < 16) {                // prefetch overlaps this chunk's MFMA
            stage_tile(Ag, &As[(c + 1) & 1][0], t, (c + 1) * 32);
            stage_tile(Bg, &Bs[(c + 1) & 1][0], t, (c + 1) * 32);
        }
        const bf16_t* Ab = &As[c & 1][0];
        const bf16_t* Bb = &Bs[c & 1][0];
        bf16x8 bh[4];
        #pragma unroll
        for (int j = 0; j < 4; ++j)
            bh[j] = *(const bf16x8*)(Bb + (wc * 64 + j * 16 + lr) * 32 + lk * 8);
        #pragma unroll
        for (int i = 0; i < 4; ++i) {
            bf16x8 ah = *(const bf16x8*)(Ab + (wr * 64 + i * 16 + lr) * 32 + lk * 8);
            #pragma unroll
            for (int j = 0; j < 4; ++j)
                acc[i][j] = __builtin_amdgcn_mfma_f32_16x16x32_bf16(
                                ah, bh[j], acc[i][j], 0, 0, 0);
        }
    }

    // Epilogue (verified R4/R5): C/D col = lane&15, row = 4*(lane>>4)+reg.
    const bool farTile = (i0 - j0) >= 256;
    const float lb0 = lb[0];
    #pragma unroll
    for (int i = 0; i < 4; ++i) {
        #pragma unroll
        for (int j = 0; j < 4; ++j) {
            int gj    = j0 + wc * 64 + j * 16 + lr;
            int cbase = (jtl << 7) + wc * 64 + j * 16 + lr;
            #pragma unroll
            for (int rg = 0; rg < 4; ++rg) {
                int gi = i0 + wr * 64 + i * 16 + lk * 4 + rg;
                float v = acc[i][j][rg] * SCALE;
                if (farTile) v += lb0;
                else {
                    int rel = gj - gi;
                    int bi  = rel < -64 ? 0 : rel + 64;
                    v += lb[min(bi, 127)];
                    if (rel > 0) v = -INFINITY;
                }
                Sc[((size_t)b * SS + gi) * HALF + cbase] = v;
            }
        }
    }
}

// ---------------------------------------------------------------------------
// APPROX scores, FALLBACK path (byte-identical to round-5 PASSING version):
// fp32 inputs, reg-staged cvt, padded LDS. Used when ws_size is too small
// for the bf16 copies.
// ---------------------------------------------------------------------------
__global__ __launch_bounds__(256, 2)
void scores_approx(const float* __restrict__ If, const float* __restrict__ Ff,
                   const float* __restrict__ lb, float* __restrict__ Sc, int h)
{
    __shared__ __align__(16) bf16_t AS[128][40];
    __shared__ __align__(16) bf16_t BS[128][40];
    const int t = threadIdx.x;

    int rt, jtl, jtg;
    decode_tile(blockIdx.x, h, rt, jtl, jtg);
    const int b  = blockIdx.z;
    const int i0 = rt << 7, j0 = jtg << 7;
    const size_t bo = (size_t)b * SS * DD;
    const float* Ag = If + bo + (size_t)i0 * DD;
    const float* Bg = Ff + bo + (size_t)j0 * DD;

    const int r0 = t >> 2;          // staged row 0..63 (+u=1 -> +64)
    const int cb = (t & 3) * 8;     // k-offset within 32-elem chunk

    const int lane = t & 63, wav = t >> 6;
    const int wr = wav >> 1, wc = wav & 1;
    const int lr = lane & 15;
    const int lk = lane >> 4;

    f32x4 acc[4][4];
    #pragma unroll
    for (int i = 0; i < 4; ++i)
        #pragma unroll
        for (int j = 0; j < 4; ++j) {
            acc[i][j][0] = 0.f; acc[i][j][1] = 0.f;
            acc[i][j][2] = 0.f; acc[i][j][3] = 0.f;
        }

    float4 aF[4], bF[4];
    #pragma unroll
    for (int u = 0; u < 2; ++u) {
        const float* ap = Ag + (size_t)(u * 64 + r0) * DD + cb;
        const float* bp = Bg + (size_t)(u * 64 + r0) * DD + cb;
        aF[2*u] = *(const float4*)ap;  aF[2*u+1] = *(const float4*)(ap + 4);
        bF[2*u] = *(const float4*)bp;  bF[2*u+1] = *(const float4*)(bp + 4);
    }

    for (int c = 0; c < 16; ++c) {
        __syncthreads();
        #pragma unroll
        for (int u = 0; u < 2; ++u) {
            float va[8] = {aF[2*u].x, aF[2*u].y, aF[2*u].z, aF[2*u].w,
                           aF[2*u+1].x, aF[2*u+1].y, aF[2*u+1].z, aF[2*u+1].w};
            float vb[8] = {bF[2*u].x, bF[2*u].y, bF[2*u].z, bF[2*u].w,
                           bF[2*u+1].x, bF[2*u+1].y, bF[2*u+1].z, bF[2*u+1].w};
            bf16x8 av8, bv8;
            #pragma unroll
            for (int e = 0; e < 8; ++e) {
                av8[e] = (bf16_t)va[e];
                bv8[e] = (bf16_t)vb[e];
            }
            int rw = u * 64 + r0;
            *(bf16x8*)&AS[rw][cb] = av8;
            *(bf16x8*)&BS[rw][cb] = bv8;
        }
        __syncthreads();
        if (c + 1 < 16) {
            int k0 = (c + 1) * 32;
            #pragma unroll
            for (int u = 0; u < 2; ++u) {
                const float* ap = Ag + (size_t)(u * 64 + r0) * DD + k0 + cb;
                const float* bp = Bg + (size_t)(u * 64 + r0) * DD + k0 + cb;
                aF[2*u] = *(const float4*)ap;  aF[2*u+1] = *(const float4*)(ap + 4);
                bF[2*u] = *(const float4*)bp;  bF[2*u+1] = *(const float4*)(bp + 4);
            }
        }
        bf16x8 bh[4];
        #pragma unroll
        for (int j = 0; j < 4; ++j)
            bh[j] = *(const bf16x8*)&BS[wc * 64 + j * 16 + lr][lk * 8];
        #pragma unroll
        for (int i = 0; i < 4; ++i) {
            bf16x8 ah = *(const bf16x8*)&AS[wr * 64 + i * 16 + lr][lk * 8];
            #pragma unroll
            for (int j = 0; j < 4; ++j)
                acc[i][j] = __builtin_amdgcn_mfma_f32_16x16x32_bf16(
                                ah, bh[j], acc[i][j], 0, 0, 0);
        }
    }

    const bool farTile = (i0 - j0) >= 256;
    const float lb0 = lb[0];
    #pragma unroll
    for (int i = 0; i < 4; ++i) {
        #pragma unroll
        for (int j = 0; j < 4; ++j) {
            int gj    = j0 + wc * 64 + j * 16 + lr;
            int cbase = (jtl << 7) + wc * 64 + j * 16 + lr;
            #pragma unroll
            for (int rg = 0; rg < 4; ++rg) {
                int gi = i0 + wr * 64 + i * 16 + lk * 4 + rg;
                float v = acc[i][j][rg] * SCALE;
                if (farTile) v += lb0;
                else {
                    int rel = gj - gi;
                    int bi  = rel < -64 ? 0 : rel + 64;
                    v += lb[min(bi, 127)];
                    if (rel > 0) v = -INFINITY;
                }
                Sc[((size_t)b * SS + gi) * HALF + cbase] = v;
            }
        }
    }
}

// ---------------------------------------------------------------------------
// Top-k with exact rescore (verified R5) + round-6 change: load-balance
// remap of wid->row. h0 rows 0..2047 are light (nv=i+1), 2048..4095 heavy
// (nv=2048); interleaving light/heavy fixes the 50%-occupancy tail seen in
// the R5 counters. Pure scheduling: per-row work and outputs unchanged.
// Barrier safety: all __syncthreads precede the h0 early-return; post-return
// code is shuffle-only.
// ---------------------------------------------------------------------------
__global__ __launch_bounds__(256)
void topk_rescore(const float* __restrict__ Sc,
                  const float* __restrict__ If, const float* __restrict__ Ff,
                  const float* __restrict__ lb,
                  const float* __restrict__ p0v_in, const int* __restrict__ p0j_in,
                  float* __restrict__ p0v_out, int* __restrict__ p0j_out,
                  float* __restrict__ out, int h)
{
    __shared__ float mv[4][64];
    __shared__ int   mj[4][64];
    __shared__ float sOv[4][32];
    __shared__ int   sOj[4][32];
    __shared__ int   sCand[4][64];

    const int lane = threadIdx.x & 63;
    const int w    = threadIdx.x >> 6;
    const int wid  = blockIdx.x * 4 + w;
    int b, i;
    if (h == 0) {
        b = wid >> 12;
        int iL = wid & 4095;                       // balance: pair light+heavy
        i = (iL & 1) ? (4095 - (iL >> 1)) : (iL >> 1);
    } else {
        b = wid >> 11;
        int iL = wid & 2047;
        int ip = (iL & 1) ? (2047 - (iL >> 1)) : (iL >> 1);
        i = HALF + ip;
    }
    const int nv = (h == 0) ? min(i + 1, HALF) : (i + 1 - HALF);  // finite count
    const size_t rb = ((size_t)b * SS + i) * HALF;
    const int l4 = lane * 4;

    int n = KSEL;
    int selj;
    if (nv <= KSEL) {
        // direct path: candidates = first 64 indices of this half.
        selj = h * HALF + lane;
    } else {
        // ---- phase 1a: load scores as monotone-sortable uint keys ----
        unsigned key[32];
        #pragma unroll
        for (int s = 0; s < 8; ++s) {
            int jb = s * 256 + l4;
            float4 f = make_float4(-INFINITY, -INFINITY, -INFINITY, -INFINITY);
            if (jb < nv) f = *(const float4*)&Sc[rb + jb];
            float vv[4] = {f.x, f.y, f.z, f.w};
            #pragma unroll
            for (int q = 0; q < 4; ++q) {
                unsigned ub = __float_as_uint(vv[q]);
                unsigned k  = (ub & 0x80000000u) ? ~ub : (ub | 0x80000000u);
                key[4*s+q] = ((jb + q) < nv) ? k : 0u;   // pads sort below -inf
            }
        }
        // ---- phase 1b: radix-descend threshold (wave-uniform control) ----
        unsigned cur = 0u;
        int csel = HALF;
        for (int bit = 31; bit >= 0 && csel > KSEL; --bit) {
            unsigned test = cur | (1u << bit);
            int cl = 0;
            #pragma unroll
            for (int c = 0; c < 32; ++c) cl += (key[c] >= test) ? 1 : 0;
            #pragma unroll
            for (int m = 1; m < 64; m <<= 1) cl += __shfl_xor(cl, m, 64);
            if (cl >= TGT) { cur = test; csel = cl; }
        }
        // ---- phase 1c: ballot-prefix compaction (cap 64) ----
        int base = 0;
        #pragma unroll
        for (int c = 0; c < 32; ++c) {
            bool surv = key[c] >= cur;
            unsigned long long mm = __ballot(surv);
            if (surv) {
                int pos = base + (int)__popcll(mm & ((1ull << lane) - 1ull));
                if (pos < KSEL)
                    sCand[w][pos] = (c >> 2) * 256 + l4 + (c & 3) + h * HALF;
            }
            base += (int)__popcll(mm);
        }
        n = min(base, KSEL);                 // n in [48, 64]
        selj = (lane < n) ? sCand[w][lane] : (h * HALF);
    }

    // ---- phase 2: exact rescore (bitwise round-0 chain) ----
    float selv;
    {
        const size_t bo = (size_t)b * SS * DD;
        const float* Irow = If + bo + (size_t)i * DD;
        const float* Frow = Ff + bo + (size_t)selj * DD;
        float acc = 0.f;
        #pragma unroll 4
        for (int k = 0; k < DD; k += 4) {
            float4 fi = *(const float4*)&Irow[k];
            float4 fj = *(const float4*)&Frow[k];
            acc = fmaf(fi.x, fj.x, acc);
            acc = fmaf(fi.y, fj.y, acc);
            acc = fmaf(fi.z, fj.z, acc);
            acc = fmaf(fi.w, fj.w, acc);
        }
        float v = acc * SCALE;
        int rel = selj - i;
        int bi  = rel < -64 ? 0 : rel + 64;
        v += lb[min(bi, 127)];
        if (rel > 0) v = -INFINITY;
        selv = v;
    }
    if (lane >= n) selv = -INFINITY;   // pad lanes (rank >= 48 > 32: inert)

    // ---- phase 3: exact top-32 of the candidates (verified R4/R5) ----
    mv[w][lane] = selv; mj[w][lane] = selj;
    __syncthreads();
    int rk = 0;
    #pragma unroll
    for (int f = 0; f < 64; ++f) {
        float fv = mv[w][f]; int fj = mj[w][f];
        rk += (fv > selv || (fv == selv && fj < selj)) ? 1 : 0;
    }
    if (rk < KTOP) { sOv[w][rk] = selv; sOj[w][rk] = selj; }
    __syncthreads();
    if (lane < KTOP) { selv = sOv[w][lane]; selj = sOj[w][lane]; }

    // ---- phase 4: partial store / merge / softmax (verified R4/R5) ----
    if (h == 0 && i >= HALF) {
        if (lane < KTOP) {
            size_t pb = ((size_t)b * HALF + (i - HALF)) * KTOP + lane;
            p0v_out[pb] = selv; p0j_out[pb] = selj;
        }
        return;
    }

    if (h == 1) {
        float p0v = 0.f; int p0j = 0;
        __syncthreads();   // phase-3 reads of mv done before merge overwrites
        if (lane < KTOP) {
            size_t pb = ((size_t)b * HALF + (i - HALF)) * KTOP + lane;
            p0v = p0v_in[pb]; p0j = p0j_in[pb];
            mv[w][lane] = p0v;         mj[w][lane] = p0j;
            mv[w][KTOP + lane] = selv; mj[w][KTOP + lane] = selj;
        }
        __syncthreads();
        int r0 = 0, r1 = 0;
        if (lane < KTOP) {
            for (int f = 0; f < 64; ++f) {
                float fv = mv[w][f]; int fj = mj[w][f];
                r0 += (fv > p0v || (fv == p0v && fj < p0j)) ? 1 : 0;
                r1 += (fv > selv || (fv == selv && fj < selj)) ? 1 : 0;
            }
        }
        __syncthreads();
        if (lane < KTOP) {
            if (r0 < KTOP) { sOv[w][r0] = p0v;  sOj[w][r0] = p0j;  }
            if (r1 < KTOP) { sOv[w][r1] = selv; sOj[w][r1] = selj; }
        }
        __syncthreads();
        if (lane < KTOP) { selv = sOv[w][lane]; selj = sOj[w][lane]; }
    }

    float mx = __shfl(selv, 0, 64);
    float e  = (lane < KTOP) ? expf(selv - mx) : 0.f;
    float sum = e;
    #pragma unroll
    for (int m = 1; m < 64; m <<= 1) sum += __shfl_xor(sum, m, 64);
    float invs = 1.0f / sum;
    if (lane < KTOP) {
        size_t ob = ((size_t)b * SS + i) * KTOP + lane;
        out[ob] = (float)selj;
        out[(size_t)BB * SS * KTOP + ob] = e * invs;
    }
}

// ---------------------------------------------------------------------------
extern "C" void kernel_launch(void* const* d_in, const int* in_sizes, int n_in,
                              void* d_out, int out_size, void* d_ws, size_t ws_size,
                              hipStream_t stream)
{
    const float* x   = (const float*)d_in[0];
    const float* Wi1 = (const float*)d_in[1];
    const float* bi1 = (const float*)d_in[2];
    const float* Wi2 = (const float*)d_in[3];
    const float* bi2 = (const float*)d_in[4];
    const float* Wf1 = (const float*)d_in[5];
    const float* bf1 = (const float*)d_in[6];
    const float* Wf2 = (const float*)d_in[7];
    const float* bf2 = (const float*)d_in[8];
    const float* lb  = (const float*)d_in[9];
    // d_in[10..13] = adaptive-k MLP (unused for outputs); d_in[14] = mask (all ones)

    const size_t NF = (size_t)BB * SS * DD;          // 4,194,304 floats
    float* ws       = (float*)d_ws;                  // base ~109 MB (R3-verified)
    float* intents  = ws;                            // NF
    float* features = ws + NF;                       // NF
    float* part0v   = ws + 2 * NF;
    int*   part0j   = (int*)(part0v + (size_t)BB * HALF * KTOP);
    float* Sc       = ws + 2 * NF + NF / 2;          // BB*SS*HALF floats (67 MB)
    float* Hi       = Sc;                            // MLP scratch inside Sc area
    float* Hf       = Sc + NF / 2;                   // (used before Sc is written)

    // Optional bf16 copies for the gload_lds scores path (+16.8 MB)
    const size_t baseFloats = 2 * NF + NF / 2 + 4 * NF;        // 6.5 NF
    const bool   useG       = ws_size >= (baseFloats + NF) * sizeof(float);
    bf16_t* IFb = (bf16_t*)(ws + baseFloats);                  // 2NF bf16 elems

    // MLP1 pair (x@W1+b1, GELU): z=0 -> intents path, z=1 -> features path
    gemm128<true ><<<dim3(DH / 128, 64, 2), 256, 0, stream>>>(
        x, x, Wi1, Wf1, bi1, bf1, Hi, Hf, DH, DD);
    // MLP2 pair (H@W2+b2)
    gemm128<false><<<dim3(DD / 128, 64, 2), 256, 0, stream>>>(
        Hi, Hf, Wi2, Wf2, bi2, bf2, intents, features, DD, DH);

    if (useG) {
        // bf16 copies of intents|features (contiguous 2NF floats)
        cvt_bf16<<<4096, 256, 0, stream>>>(intents, IFb);
        scores_approx_g<<<dim3(392, 1, BB), 256, 0, stream>>>(
            IFb, IFb + NF, lb, Sc, 0);
    } else {
        scores_approx<<<dim3(392, 1, BB), 256, 0, stream>>>(
            intents, features, lb, Sc, 0);
    }
    topk_rescore<<<(BB * SS) / 4, 256, 0, stream>>>(Sc, intents, features, lb,
                                                    part0v, part0j, part0v, part0j,
                                                    (float*)d_out, 0);
    if (useG) {
        scores_approx_g<<<dim3(136, 1, BB), 256, 0, stream>>>(
            IFb, IFb + NF, lb, Sc, 1);
    } else {
        scores_approx<<<dim3(136, 1, BB), 256, 0, stream>>>(
            intents, features, lb, Sc, 1);
    }
    topk_rescore<<<(BB * HALF) / 4, 256, 0, stream>>>(Sc, intents, features, lb,
                                                      part0v, part0j, part0v, part0j,
                                                      (float*)d_out, 1);
}

// Round 8
// 484.996 us; speedup vs baseline: 2.1015x; 1.1100x over previous
//
#include <hip/hip_runtime.h>
#include <math.h>

// Problem constants (B=2, S=4096, D=512, MAXC=32, BIAS_LEN=128, TEMP=1)
#define BB   2
#define SS   4096
#define DD   512
#define DH   256      // D/2
#define KTOP 32
#define KSEL 64       // candidate slots (one per lane)
#define TGT  48       // threshold target: count(key >= T) >= TGT (margin 16 ranks)
#define HALF 2048     // j processed in two halves to bound workspace
#define SCALE 0.044194173824159216f   // 1/sqrt(512)

typedef __bf16 bf16_t;
typedef bf16_t bf16x8 __attribute__((ext_vector_type(8)));
typedef float  f32x4  __attribute__((ext_vector_type(4)));

// decode row of triangular tile list: q in [0, r_max*(r_max+1)/2)
__device__ __forceinline__ int tri_row(int q) {
    int r = (int)((sqrtf(8.0f * q + 1.0f) - 1.0f) * 0.5f);
    while ((r + 1) * (r + 2) / 2 <= q) ++r;
    while (r * (r + 1) / 2 > q) --r;
    return r;
}

// tile-id decode shared by both scores kernels (verified R0..R7)
__device__ __forceinline__ void decode_tile(int id, int h, int& rt, int& jtl, int& jtg) {
    if (h == 0) {
        if (id < 256) { rt = 16 + (id >> 4); jtl = id & 15; }
        else { int q = id - 256; rt = tri_row(q); jtl = q - rt * (rt + 1) / 2; }
        jtg = jtl;
    } else {
        int r = tri_row(id); rt = 16 + r;
        jtl = id - r * (r + 1) / 2; jtg = jtl + 16;
    }
}

// ---------------------------------------------------------------------------
// MLP GEMM v8 (unchanged, verified): 128x128 tile, 8x8 micro, FP32 VALU.
// ---------------------------------------------------------------------------
template<bool GELU>
__global__ __launch_bounds__(256)
void gemm128(const float* __restrict__ A0, const float* __restrict__ A1,
             const float* __restrict__ W0, const float* __restrict__ W1,
             const float* __restrict__ b0, const float* __restrict__ b1,
             float* __restrict__ C0, float* __restrict__ C1,
             int N, int K)
{
    __shared__ float As[32][132];   // [k][m]
    __shared__ float Ws[32][132];   // [k][n]
    const int t = threadIdx.x;
    const int z = blockIdx.z;
    const float* A    = z ? A1 : A0;
    const float* W    = z ? W1 : W0;
    const float* bias = z ? b1 : b0;
    float*       C    = z ? C1 : C0;
    const int n0 = blockIdx.x * 128;
    const int m0 = blockIdx.y * 128;

    const int kq = t & 7;          // A stager: k-quad within chunk
    const int rr = t >> 3;         // A stager: row 0..31 (+u*32)
    const int wkr = t >> 3;        // W stager: k-row 0..31
    const int wnc = (t & 7) * 16;  // W stager: col group (16 cols = 4 float4)
    const float* Ab = A + (size_t)m0 * K;
    const float* Wb = W + (size_t)0 * N + n0;

    const int lane = t & 63, wav = t >> 6;
    const int wr = wav >> 1, wc = wav & 1;     // wave 2x2 over 64x64 regions
    const int li = lane >> 3, lj = lane & 7;   // 8x8 lane grid

    float acc[8][8] = {};
    float4 aR[4], wR[4];
    #pragma unroll
    for (int u = 0; u < 4; ++u) {              // prologue: chunk 0 -> regs
        int r = u * 32 + rr;
        aR[u] = *(const float4*)&Ab[(size_t)r * K + 4 * kq];
        wR[u] = *(const float4*)&Wb[(size_t)wkr * N + wnc + 4 * u];
    }
    const int nch = K >> 5;
    for (int c = 0; c < nch; ++c) {
        __syncthreads();
        #pragma unroll
        for (int u = 0; u < 4; ++u) {          // regs -> LDS
            int r = u * 32 + rr;
            As[4*kq+0][r] = aR[u].x; As[4*kq+1][r] = aR[u].y;
            As[4*kq+2][r] = aR[u].z; As[4*kq+3][r] = aR[u].w;
            *(float4*)&Ws[wkr][wnc + 4 * u] = wR[u];
        }
        __syncthreads();
        if (c + 1 < nch) {                     // prefetch next chunk
            int k0 = (c + 1) * 32;
            #pragma unroll
            for (int u = 0; u < 4; ++u) {
                int r = u * 32 + rr;
                aR[u] = *(const float4*)&Ab[(size_t)r * K + k0 + 4 * kq];
                wR[u] = *(const float4*)&Wb[(size_t)(k0 + wkr) * N + wnc + 4 * u];
            }
        }
        #pragma unroll
        for (int kk = 0; kk < 32; ++kk) {      // conflict-free: 8 addrs x 8-bcast
            float4 a0 = *(const float4*)&As[kk][wr * 64 + li * 8];
            float4 a1 = *(const float4*)&As[kk][wr * 64 + li * 8 + 4];
            float4 b0v = *(const float4*)&Ws[kk][wc * 64 + lj * 8];
            float4 b1v = *(const float4*)&Ws[kk][wc * 64 + lj * 8 + 4];
            float av[8] = {a0.x,a0.y,a0.z,a0.w,a1.x,a1.y,a1.z,a1.w};
            float bv[8] = {b0v.x,b0v.y,b0v.z,b0v.w,b1v.x,b1v.y,b1v.z,b1v.w};
            #pragma unroll
            for (int ri = 0; ri < 8; ++ri)
                #pragma unroll
                for (int rj = 0; rj < 8; ++rj)
                    acc[ri][rj] = fmaf(av[ri], bv[rj], acc[ri][rj]);
        }
    }

    const int nb = n0 + wc * 64 + lj * 8;
    float bv0[8];
    *(float4*)&bv0[0] = *(const float4*)&bias[nb];
    *(float4*)&bv0[4] = *(const float4*)&bias[nb + 4];
    #pragma unroll
    for (int ri = 0; ri < 8; ++ri) {
        int m = m0 + wr * 64 + li * 8 + ri;
        float o[8];
        #pragma unroll
        for (int rj = 0; rj < 8; ++rj) {
            float v = acc[ri][rj] + bv0[rj];   // same op order as R3: acc + bias
            if (GELU) v = 0.5f * v * (1.0f + erff(v * 0.7071067811865475f));
            o[rj] = v;
        }
        *(float4*)&C[(size_t)m * N + nb]     = make_float4(o[0],o[1],o[2],o[3]);
        *(float4*)&C[(size_t)m * N + nb + 4] = make_float4(o[4],o[5],o[6],o[7]);
    }
}

// ---------------------------------------------------------------------------
// fp32 -> bf16 copy (RNE cast, identical values to the in-kernel cvt).
// ---------------------------------------------------------------------------
__global__ __launch_bounds__(256)
void cvt_bf16(const float* __restrict__ src, bf16_t* __restrict__ dst)
{
    size_t idx = ((size_t)blockIdx.x * 256 + threadIdx.x) * 8;
    float4 f0 = *(const float4*)&src[idx];
    float4 f1 = *(const float4*)&src[idx + 4];
    float v[8] = {f0.x, f0.y, f0.z, f0.w, f1.x, f1.y, f1.z, f1.w};
    bf16x8 hv;
    #pragma unroll
    for (int j = 0; j < 8; ++j) hv[j] = (bf16_t)v[j];
    *(bf16x8*)&dst[idx] = hv;
}

// ---------------------------------------------------------------------------
// APPROX scores (verified R7): bf16 inputs + global_load_lds(16B) staging,
// m97 schedule (double-buffered [128][32] linear LDS, 1 barrier/chunk).
// ---------------------------------------------------------------------------
__device__ __forceinline__ void stage_tile(const bf16_t* __restrict__ g,
                                           bf16_t* lds, int t, int k0)
{
    const int r0 = t >> 2;          // global row 0..63 (+64 for inst 1)
    const int cb = (t & 3) * 8;     // element offset within 32-elem slice
    const int wb = (t >> 6) * 512;  // wave-uniform LDS element base
    #pragma unroll
    for (int inst = 0; inst < 2; ++inst) {
        const bf16_t* gp = g + (size_t)(inst * 64 + r0) * DD + (k0 + cb);
        bf16_t* lp = lds + inst * 2048 + wb;   // + lane*8 elems added by HW
        __builtin_amdgcn_global_load_lds(
            (const __attribute__((address_space(1))) void*)gp,
            (__attribute__((address_space(3))) void*)lp, 16, 0, 0);
    }
}

__global__ __launch_bounds__(256, 2)
void scores_approx_g(const bf16_t* __restrict__ Ib, const bf16_t* __restrict__ Fb,
                     const float* __restrict__ lb, float* __restrict__ Sc, int h)
{
    __shared__ bf16_t As[2][128 * 32];
    __shared__ bf16_t Bs[2][128 * 32];
    const int t = threadIdx.x;

    int rt, jtl, jtg;
    decode_tile(blockIdx.x, h, rt, jtl, jtg);
    const int b  = blockIdx.z;
    const int i0 = rt << 7, j0 = jtg << 7;
    const size_t bo = (size_t)b * SS * DD;
    const bf16_t* Ag = Ib + bo + (size_t)i0 * DD;
    const bf16_t* Bg = Fb + bo + (size_t)j0 * DD;

    const int lane = t & 63, wav = t >> 6;
    const int wr = wav >> 1, wc = wav & 1;   // 2x2 waves over 64x64 regions
    const int lr = lane & 15;                // fragment row (A) / col (B)
    const int lk = lane >> 4;                // k-group 0..3

    f32x4 acc[4][4];
    #pragma unroll
    for (int i = 0; i < 4; ++i)
        #pragma unroll
        for (int j = 0; j < 4; ++j) {
            acc[i][j][0] = 0.f; acc[i][j][1] = 0.f;
            acc[i][j][2] = 0.f; acc[i][j][3] = 0.f;
        }

    stage_tile(Ag, &As[0][0], t, 0);
    stage_tile(Bg, &Bs[0][0], t, 0);
    for (int c = 0; c < 16; ++c) {
        __syncthreads();                 // drains vmcnt: buf[c&1] ready
        if (c + 1 < 16) {                // prefetch overlaps this chunk's MFMA
            stage_tile(Ag, &As[(c + 1) & 1][0], t, (c + 1) * 32);
            stage_tile(Bg, &Bs[(c + 1) & 1][0], t, (c + 1) * 32);
        }
        const bf16_t* Ab = &As[c & 1][0];
        const bf16_t* Bb = &Bs[c & 1][0];
        bf16x8 bh[4];
        #pragma unroll
        for (int j = 0; j < 4; ++j)
            bh[j] = *(const bf16x8*)(Bb + (wc * 64 + j * 16 + lr) * 32 + lk * 8);
        #pragma unroll
        for (int i = 0; i < 4; ++i) {
            bf16x8 ah = *(const bf16x8*)(Ab + (wr * 64 + i * 16 + lr) * 32 + lk * 8);
            #pragma unroll
            for (int j = 0; j < 4; ++j)
                acc[i][j] = __builtin_amdgcn_mfma_f32_16x16x32_bf16(
                                ah, bh[j], acc[i][j], 0, 0, 0);
        }
    }

    // Epilogue (verified R4..R7): C/D col = lane&15, row = 4*(lane>>4)+reg.
    const bool farTile = (i0 - j0) >= 256;
    const float lb0 = lb[0];
    #pragma unroll
    for (int i = 0; i < 4; ++i) {
        #pragma unroll
        for (int j = 0; j < 4; ++j) {
            int gj    = j0 + wc * 64 + j * 16 + lr;
            int cbase = (jtl << 7) + wc * 64 + j * 16 + lr;
            #pragma unroll
            for (int rg = 0; rg < 4; ++rg) {
                int gi = i0 + wr * 64 + i * 16 + lk * 4 + rg;
                float v = acc[i][j][rg] * SCALE;
                if (farTile) v += lb0;
                else {
                    int rel = gj - gi;
                    int bi  = rel < -64 ? 0 : rel + 64;
                    v += lb[min(bi, 127)];
                    if (rel > 0) v = -INFINITY;
                }
                Sc[((size_t)b * SS + gi) * HALF + cbase] = v;
            }
        }
    }
}

// ---------------------------------------------------------------------------
// APPROX scores, FALLBACK path (byte-identical to round-5 PASSING version).
// ---------------------------------------------------------------------------
__global__ __launch_bounds__(256, 2)
void scores_approx(const float* __restrict__ If, const float* __restrict__ Ff,
                   const float* __restrict__ lb, float* __restrict__ Sc, int h)
{
    __shared__ __align__(16) bf16_t AS[128][40];
    __shared__ __align__(16) bf16_t BS[128][40];
    const int t = threadIdx.x;

    int rt, jtl, jtg;
    decode_tile(blockIdx.x, h, rt, jtl, jtg);
    const int b  = blockIdx.z;
    const int i0 = rt << 7, j0 = jtg << 7;
    const size_t bo = (size_t)b * SS * DD;
    const float* Ag = If + bo + (size_t)i0 * DD;
    const float* Bg = Ff + bo + (size_t)j0 * DD;

    const int r0 = t >> 2;          // staged row 0..63 (+u=1 -> +64)
    const int cb = (t & 3) * 8;     // k-offset within 32-elem chunk

    const int lane = t & 63, wav = t >> 6;
    const int wr = wav >> 1, wc = wav & 1;
    const int lr = lane & 15;
    const int lk = lane >> 4;

    f32x4 acc[4][4];
    #pragma unroll
    for (int i = 0; i < 4; ++i)
        #pragma unroll
        for (int j = 0; j < 4; ++j) {
            acc[i][j][0] = 0.f; acc[i][j][1] = 0.f;
            acc[i][j][2] = 0.f; acc[i][j][3] = 0.f;
        }

    float4 aF[4], bF[4];
    #pragma unroll
    for (int u = 0; u < 2; ++u) {
        const float* ap = Ag + (size_t)(u * 64 + r0) * DD + cb;
        const float* bp = Bg + (size_t)(u * 64 + r0) * DD + cb;
        aF[2*u] = *(const float4*)ap;  aF[2*u+1] = *(const float4*)(ap + 4);
        bF[2*u] = *(const float4*)bp;  bF[2*u+1] = *(const float4*)(bp + 4);
    }

    for (int c = 0; c < 16; ++c) {
        __syncthreads();
        #pragma unroll
        for (int u = 0; u < 2; ++u) {
            float va[8] = {aF[2*u].x, aF[2*u].y, aF[2*u].z, aF[2*u].w,
                           aF[2*u+1].x, aF[2*u+1].y, aF[2*u+1].z, aF[2*u+1].w};
            float vb[8] = {bF[2*u].x, bF[2*u].y, bF[2*u].z, bF[2*u].w,
                           bF[2*u+1].x, bF[2*u+1].y, bF[2*u+1].z, bF[2*u+1].w};
            bf16x8 av8, bv8;
            #pragma unroll
            for (int e = 0; e < 8; ++e) {
                av8[e] = (bf16_t)va[e];
                bv8[e] = (bf16_t)vb[e];
            }
            int rw = u * 64 + r0;
            *(bf16x8*)&AS[rw][cb] = av8;
            *(bf16x8*)&BS[rw][cb] = bv8;
        }
        __syncthreads();
        if (c + 1 < 16) {
            int k0 = (c + 1) * 32;
            #pragma unroll
            for (int u = 0; u < 2; ++u) {
                const float* ap = Ag + (size_t)(u * 64 + r0) * DD + k0 + cb;
                const float* bp = Bg + (size_t)(u * 64 + r0) * DD + k0 + cb;
                aF[2*u] = *(const float4*)ap;  aF[2*u+1] = *(const float4*)(ap + 4);
                bF[2*u] = *(const float4*)bp;  bF[2*u+1] = *(const float4*)(bp + 4);
            }
        }
        bf16x8 bh[4];
        #pragma unroll
        for (int j = 0; j < 4; ++j)
            bh[j] = *(const bf16x8*)&BS[wc * 64 + j * 16 + lr][lk * 8];
        #pragma unroll
        for (int i = 0; i < 4; ++i) {
            bf16x8 ah = *(const bf16x8*)&AS[wr * 64 + i * 16 + lr][lk * 8];
            #pragma unroll
            for (int j = 0; j < 4; ++j)
                acc[i][j] = __builtin_amdgcn_mfma_f32_16x16x32_bf16(
                                ah, bh[j], acc[i][j], 0, 0, 0);
        }
    }

    const bool farTile = (i0 - j0) >= 256;
    const float lb0 = lb[0];
    #pragma unroll
    for (int i = 0; i < 4; ++i) {
        #pragma unroll
        for (int j = 0; j < 4; ++j) {
            int gj    = j0 + wc * 64 + j * 16 + lr;
            int cbase = (jtl << 7) + wc * 64 + j * 16 + lr;
            #pragma unroll
            for (int rg = 0; rg < 4; ++rg) {
                int gi = i0 + wr * 64 + i * 16 + lk * 4 + rg;
                float v = acc[i][j][rg] * SCALE;
                if (farTile) v += lb0;
                else {
                    int rel = gj - gi;
                    int bi  = rel < -64 ? 0 : rel + 64;
                    v += lb[min(bi, 127)];
                    if (rel > 0) v = -INFINITY;
                }
                Sc[((size_t)b * SS + gi) * HALF + cbase] = v;
            }
        }
    }
}

// ---------------------------------------------------------------------------
// Top-k with exact rescore. Round-8 change: ONE WAVE PER BLOCK (64 threads).
// R7's counters falsified the load-imbalance theory (remap: 166->169 us,
// occupancy still 50%). New theory: block-wide __syncthreads convoys 4
// unrelated rows through the long-latency phases (64-line gathers in the
// rescore, dependent shuffle-butterflies in the radix, 512-deep fmaf chain)
// -- the slowest wave stalls all four at every barrier. With 1-wave blocks
// the barriers become cheap intra-wave waits and rows retire independently.
// Row mapping = R5-verified identity (remap removed: falsified, neutral).
// Per-lane arithmetic identical -> outputs bitwise unchanged.
// ---------------------------------------------------------------------------
__global__ __launch_bounds__(64)
void topk_rescore(const float* __restrict__ Sc,
                  const float* __restrict__ If, const float* __restrict__ Ff,
                  const float* __restrict__ lb,
                  const float* __restrict__ p0v_in, const int* __restrict__ p0j_in,
                  float* __restrict__ p0v_out, int* __restrict__ p0j_out,
                  float* __restrict__ out, int h)
{
    __shared__ float mv[64];
    __shared__ int   mj[64];
    __shared__ float sOv[32];
    __shared__ int   sOj[32];
    __shared__ int   sCand[64];

    const int lane = threadIdx.x;
    const int wid  = blockIdx.x;
    int b, i;
    if (h == 0) { b = wid >> 12; i = wid & 4095; }
    else        { b = wid >> 11; i = HALF + (wid & 2047); }
    const int nv = (h == 0) ? min(i + 1, HALF) : (i + 1 - HALF);  // finite count
    const size_t rb = ((size_t)b * SS + i) * HALF;
    const int l4 = lane * 4;

    int n = KSEL;
    int selj;
    if (nv <= KSEL) {
        // direct path: candidates = first 64 indices of this half.
        selj = h * HALF + lane;
    } else {
        // ---- phase 1a: load scores as monotone-sortable uint keys ----
        unsigned key[32];
        #pragma unroll
        for (int s = 0; s < 8; ++s) {
            int jb = s * 256 + l4;
            float4 f = make_float4(-INFINITY, -INFINITY, -INFINITY, -INFINITY);
            if (jb < nv) f = *(const float4*)&Sc[rb + jb];
            float vv[4] = {f.x, f.y, f.z, f.w};
            #pragma unroll
            for (int q = 0; q < 4; ++q) {
                unsigned ub = __float_as_uint(vv[q]);
                unsigned k  = (ub & 0x80000000u) ? ~ub : (ub | 0x80000000u);
                key[4*s+q] = ((jb + q) < nv) ? k : 0u;   // pads sort below -inf
            }
        }
        // ---- phase 1b: radix-descend threshold (wave-uniform control) ----
        unsigned cur = 0u;
        int csel = HALF;
        for (int bit = 31; bit >= 0 && csel > KSEL; --bit) {
            unsigned test = cur | (1u << bit);
            int cl = 0;
            #pragma unroll
            for (int c = 0; c < 32; ++c) cl += (key[c] >= test) ? 1 : 0;
            #pragma unroll
            for (int m = 1; m < 64; m <<= 1) cl += __shfl_xor(cl, m, 64);
            if (cl >= TGT) { cur = test; csel = cl; }
        }
        // ---- phase 1c: ballot-prefix compaction (cap 64) ----
        int base = 0;
        #pragma unroll
        for (int c = 0; c < 32; ++c) {
            bool surv = key[c] >= cur;
            unsigned long long mm = __ballot(surv);
            if (surv) {
                int pos = base + (int)__popcll(mm & ((1ull << lane) - 1ull));
                if (pos < KSEL)
                    sCand[pos] = (c >> 2) * 256 + l4 + (c & 3) + h * HALF;
            }
            base += (int)__popcll(mm);
        }
        n = min(base, KSEL);                 // n in [48, 64]
        __syncthreads();                     // intra-wave: sCand visible
        selj = (lane < n) ? sCand[lane] : (h * HALF);
    }

    // ---- phase 2: exact rescore (bitwise round-0 chain; unroll widened) ----
    float selv;
    {
        const size_t bo = (size_t)b * SS * DD;
        const float* Irow = If + bo + (size_t)i * DD;
        const float* Frow = Ff + bo + (size_t)selj * DD;
        float acc = 0.f;
        #pragma unroll 8
        for (int k = 0; k < DD; k += 4) {
            float4 fi = *(const float4*)&Irow[k];
            float4 fj = *(const float4*)&Frow[k];
            acc = fmaf(fi.x, fj.x, acc);
            acc = fmaf(fi.y, fj.y, acc);
            acc = fmaf(fi.z, fj.z, acc);
            acc = fmaf(fi.w, fj.w, acc);
        }
        float v = acc * SCALE;
        int rel = selj - i;
        int bi  = rel < -64 ? 0 : rel + 64;
        v += lb[min(bi, 127)];
        if (rel > 0) v = -INFINITY;
        selv = v;
    }
    if (lane >= n) selv = -INFINITY;   // pad lanes (rank >= 48 > 32: inert)

    // ---- phase 3: exact top-32 of the candidates (verified R4..R7) ----
    mv[lane] = selv; mj[lane] = selj;
    __syncthreads();
    int rk = 0;
    #pragma unroll
    for (int f = 0; f < 64; ++f) {
        float fv = mv[f]; int fj = mj[f];
        rk += (fv > selv || (fv == selv && fj < selj)) ? 1 : 0;
    }
    if (rk < KTOP) { sOv[rk] = selv; sOj[rk] = selj; }
    __syncthreads();
    if (lane < KTOP) { selv = sOv[lane]; selj = sOj[lane]; }

    // ---- phase 4: partial store / merge / softmax (verified R4..R7) ----
    if (h == 0 && i >= HALF) {
        if (lane < KTOP) {
            size_t pb = ((size_t)b * HALF + (i - HALF)) * KTOP + lane;
            p0v_out[pb] = selv; p0j_out[pb] = selj;
        }
        return;
    }

    if (h == 1) {
        float p0v = 0.f; int p0j = 0;
        __syncthreads();   // phase-3 reads of mv done before merge overwrites
        if (lane < KTOP) {
            size_t pb = ((size_t)b * HALF + (i - HALF)) * KTOP + lane;
            p0v = p0v_in[pb]; p0j = p0j_in[pb];
            mv[lane] = p0v;         mj[lane] = p0j;
            mv[KTOP + lane] = selv; mj[KTOP + lane] = selj;
        }
        __syncthreads();
        int r0 = 0, r1 = 0;
        if (lane < KTOP) {
            for (int f = 0; f < 64; ++f) {
                float fv = mv[f]; int fj = mj[f];
                r0 += (fv > p0v || (fv == p0v && fj < p0j)) ? 1 : 0;
                r1 += (fv > selv || (fv == selv && fj < selj)) ? 1 : 0;
            }
        }
        __syncthreads();
        if (lane < KTOP) {
            if (r0 < KTOP) { sOv[r0] = p0v;  sOj[r0] = p0j;  }
            if (r1 < KTOP) { sOv[r1] = selv; sOj[r1] = selj; }
        }
        __syncthreads();
        if (lane < KTOP) { selv = sOv[lane]; selj = sOj[lane]; }
    }

    float mx = __shfl(selv, 0, 64);
    float e  = (lane < KTOP) ? expf(selv - mx) : 0.f;
    float sum = e;
    #pragma unroll
    for (int m = 1; m < 64; m <<= 1) sum += __shfl_xor(sum, m, 64);
    float invs = 1.0f / sum;
    if (lane < KTOP) {
        size_t ob = ((size_t)b * SS + i) * KTOP + lane;
        out[ob] = (float)selj;
        out[(size_t)BB * SS * KTOP + ob] = e * invs;
    }
}

// ---------------------------------------------------------------------------
extern "C" void kernel_launch(void* const* d_in, const int* in_sizes, int n_in,
                              void* d_out, int out_size, void* d_ws, size_t ws_size,
                              hipStream_t stream)
{
    const float* x   = (const float*)d_in[0];
    const float* Wi1 = (const float*)d_in[1];
    const float* bi1 = (const float*)d_in[2];
    const float* Wi2 = (const float*)d_in[3];
    const float* bi2 = (const float*)d_in[4];
    const float* Wf1 = (const float*)d_in[5];
    const float* bf1 = (const float*)d_in[6];
    const float* Wf2 = (const float*)d_in[7];
    const float* bf2 = (const float*)d_in[8];
    const float* lb  = (const float*)d_in[9];
    // d_in[10..13] = adaptive-k MLP (unused for outputs); d_in[14] = mask (all ones)

    const size_t NF = (size_t)BB * SS * DD;          // 4,194,304 floats
    float* ws       = (float*)d_ws;                  // base ~109 MB (R3-verified)
    float* intents  = ws;                            // NF
    float* features = ws + NF;                       // NF
    float* part0v   = ws + 2 * NF;
    int*   part0j   = (int*)(part0v + (size_t)BB * HALF * KTOP);
    float* Sc       = ws + 2 * NF + NF / 2;          // BB*SS*HALF floats (67 MB)
    float* Hi       = Sc;                            // MLP scratch inside Sc area
    float* Hf       = Sc + NF / 2;                   // (used before Sc is written)

    // Optional bf16 copies for the gload_lds scores path (+16.8 MB)
    const size_t baseFloats = 2 * NF + NF / 2 + 4 * NF;        // 6.5 NF
    const bool   useG       = ws_size >= (baseFloats + NF) * sizeof(float);
    bf16_t* IFb = (bf16_t*)(ws + baseFloats);                  // 2NF bf16 elems

    // MLP1 pair (x@W1+b1, GELU): z=0 -> intents path, z=1 -> features path
    gemm128<true ><<<dim3(DH / 128, 64, 2), 256, 0, stream>>>(
        x, x, Wi1, Wf1, bi1, bf1, Hi, Hf, DH, DD);
    // MLP2 pair (H@W2+b2)
    gemm128<false><<<dim3(DD / 128, 64, 2), 256, 0, stream>>>(
        Hi, Hf, Wi2, Wf2, bi2, bf2, intents, features, DD, DH);

    if (useG) {
        // bf16 copies of intents|features (contiguous 2NF floats)
        cvt_bf16<<<4096, 256, 0, stream>>>(intents, IFb);
        scores_approx_g<<<dim3(392, 1, BB), 256, 0, stream>>>(
            IFb, IFb + NF, lb, Sc, 0);
    } else {
        scores_approx<<<dim3(392, 1, BB), 256, 0, stream>>>(
            intents, features, lb, Sc, 0);
    }
    topk_rescore<<<BB * SS, 64, 0, stream>>>(Sc, intents, features, lb,
                                             part0v, part0j, part0v, part0j,
                                             (float*)d_out, 0);
    if (useG) {
        scores_approx_g<<<dim3(136, 1, BB), 256, 0, stream>>>(
            IFb, IFb + NF, lb, Sc, 1);
    } else {
        scores_approx<<<dim3(136, 1, BB), 256, 0, stream>>>(
            intents, features, lb, Sc, 1);
    }
    topk_rescore<<<BB * HALF, 64, 0, stream>>>(Sc, intents, features, lb,
                                               part0v, part0j, part0v, part0j,
                                               (float*)d_out, 1);
}